// Round 12
// baseline (169.554 us; speedup 1.0000x reference)
//
#include <hip/hip_runtime.h>

#define L 2048
#define HSZ 1024
#define HDIM 64
// 32 head-panels total (N=2 batches x 16 heads), each a contiguous [2048][64]

typedef float f32x4 __attribute__((ext_vector_type(4)));
typedef short short8v __attribute__((ext_vector_type(8)));

static __device__ __forceinline__ unsigned short f2bf(float f) {
    unsigned int u = __builtin_bit_cast(unsigned int, f);
    u += 0x7FFFu + ((u >> 16) & 1u);   // RNE
    return (unsigned short)(u >> 16);
}
static __device__ __forceinline__ float bf2f(unsigned short u) {
    return __builtin_bit_cast(float, (unsigned int)u << 16);
}
static __device__ __forceinline__ unsigned int cvt_pk_bf16(float lo, float hi) {
    unsigned int r;
    asm("v_cvt_pk_bf16_f32 %0, %1, %2" : "=v"(r) : "v"(lo), "v"(hi));
    return r;
}
static __device__ __forceinline__ void gload_lds16(const void* g, void* l) {
    __builtin_amdgcn_global_load_lds(
        (const __attribute__((address_space(1))) unsigned int*)g,
        (__attribute__((address_space(3))) unsigned int*)l, 16, 0, 0);
}

// ---------------------------------------------------------------------------
// Weights: Wt4[z][n][k] = bf16(W_z[k][n]) for z in {q,k,v,o}.
// ---------------------------------------------------------------------------
__global__ __launch_bounds__(256) void wtrans_kernel(
    const float* __restrict__ W0, const float* __restrict__ W1,
    const float* __restrict__ W2, const float* __restrict__ W3,
    unsigned short* __restrict__ Wt4)
{
    const float* W;
    int z = blockIdx.z;
    if (z == 0) W = W0; else if (z == 1) W = W1; else if (z == 2) W = W2; else W = W3;
    unsigned short* T = Wt4 + (size_t)z * HSZ * HSZ;

    __shared__ __align__(16) unsigned short tl[64][72];
    int t = threadIdx.x;
    int k0 = blockIdx.y * 64, n0 = blockIdx.x * 64;

    int kl = t >> 2, nc = (t & 3) * 16;
    const float* src = W + (size_t)(k0 + kl) * HSZ + n0 + nc;
#pragma unroll
    for (int q = 0; q < 4; q++) {
        float4 v = ((const float4*)src)[q];
        tl[kl][nc + q * 4 + 0] = f2bf(v.x);
        tl[kl][nc + q * 4 + 1] = f2bf(v.y);
        tl[kl][nc + q * 4 + 2] = f2bf(v.z);
        tl[kl][nc + q * 4 + 3] = f2bf(v.w);
    }
    __syncthreads();
    int nl = t >> 2, kc = (t & 3) * 16;
    unsigned short tmp[16];
#pragma unroll
    for (int e = 0; e < 16; e++) tmp[e] = tl[kc + e][nl];
    unsigned short* dst = T + (size_t)(n0 + nl) * HSZ + k0 + kc;
    ((uint4*)dst)[0] = *(uint4*)&tmp[0];
    ((uint4*)dst)[1] = *(uint4*)&tmp[8];
}

// ---------------------------------------------------------------------------
// Convert H_q/H_k/H_v fp32 -> bf16 into contiguous Hbf[3][4096][1024].
// ---------------------------------------------------------------------------
__global__ __launch_bounds__(256) void hconv_kernel(
    const float* __restrict__ H0, const float* __restrict__ H1,
    const float* __restrict__ H2, unsigned short* __restrict__ Hbf)
{
    int z = blockIdx.y;
    const float* S = (z == 0) ? H0 : (z == 1) ? H1 : H2;
    size_t base = ((size_t)blockIdx.x * 256 + threadIdx.x) * 8;
    unsigned short* D = Hbf + (size_t)z * (4096 * 1024) + base;
    float4 a = *(const float4*)(S + base);
    float4 b = *(const float4*)(S + base + 4);
    unsigned short o[8] = {f2bf(a.x), f2bf(a.y), f2bf(a.z), f2bf(a.w),
                           f2bf(b.x), f2bf(b.y), f2bf(b.z), f2bf(b.w)};
    *(uint4*)D = *(const uint4*)o;
}

// ---------------------------------------------------------------------------
// QKV GEMM (bf16 out), single-barrier dbuf pipeline, XCD-slab swizzle.
// ---------------------------------------------------------------------------
__global__ __launch_bounds__(256) void gemm_glds_kernel(
    const unsigned short* __restrict__ A, const unsigned short* __restrict__ B,
    const float* __restrict__ bias0, const float* __restrict__ bias1,
    const float* __restrict__ bias2, float scale01, float scale2,
    unsigned short* __restrict__ outbase)
{
    __shared__ __align__(16) unsigned short As[2][4096];
    __shared__ __align__(16) unsigned short Bs[2][4096];

    int raw = blockIdx.x;
    int xcd = raw & 7, idx = raw >> 3;       // idx in [0,96)
    int mb = (xcd * 4 + (idx & 3)) * 128;    // 4 mb-slabs per XCD
    int col = idx >> 2;                      // 0..23
    int proj = col >> 3;
    int nb = (col & 7) * 128;

    int t = threadIdx.x;
    int lane = t & 63, w = t >> 6;
    int lr = lane & 15, lg = lane >> 4;
    int wm = (w >> 1) * 64, wn = (w & 1) * 64;

    const unsigned short* Ap = A + (size_t)proj * (4096 * 1024);
    const unsigned short* Bp = B + (size_t)proj * (1024 * 1024);
    const float* bias = (proj == 0) ? bias0 : (proj == 1) ? bias1 : bias2;
    float scale = (proj < 2) ? scale01 : scale2;

    int c0 = w * 64 + lane;
    int r0 = c0 >> 2, e0 = (c0 & 3) * 8;
    int r1 = r0 + 64;
    const unsigned short* gA0 = Ap + (size_t)(mb + r0) * HSZ + e0;
    const unsigned short* gA1 = Ap + (size_t)(mb + r1) * HSZ + e0;
    const unsigned short* gB0 = Bp + (size_t)(nb + r0) * HSZ + e0;
    const unsigned short* gB1 = Bp + (size_t)(nb + r1) * HSZ + e0;

    f32x4 acc[4][4] = {};

    auto stage = [&](int buf, int kt) {
        gload_lds16(gA0 + kt, &As[buf][w * 512]);
        gload_lds16(gA1 + kt, &As[buf][2048 + w * 512]);
        gload_lds16(gB0 + kt, &Bs[buf][w * 512]);
        gload_lds16(gB1 + kt, &Bs[buf][2048 + w * 512]);
    };

    stage(0, 0);
    __syncthreads();

    int buf = 0;
    for (int kt = 0; kt < HSZ; kt += 32) {
        if (kt + 32 < HSZ) stage(buf ^ 1, kt + 32);

        short8v af[4], bfv[4];
#pragma unroll
        for (int s = 0; s < 4; s++) {
            af[s]  = *(const short8v*)&As[buf][(wm + s * 16 + lr) * 32 + lg * 8];
            bfv[s] = *(const short8v*)&Bs[buf][(wn + s * 16 + lr) * 32 + lg * 8];
        }
#pragma unroll
        for (int i = 0; i < 4; i++)
#pragma unroll
            for (int j = 0; j < 4; j++)
                acc[i][j] = __builtin_amdgcn_mfma_f32_16x16x32_bf16(af[i], bfv[j], acc[i][j], 0, 0, 0);
        __syncthreads();   // drains stage vmcnt + all reads of buf
        buf ^= 1;
    }

#pragma unroll
    for (int j = 0; j < 4; j++) {
        int colo = nb + wn + j * 16 + lr;
        float bv = bias[colo];
#pragma unroll
        for (int i = 0; i < 4; i++) {
            int row0 = mb + wm + i * 16 + lg * 4;
#pragma unroll
            for (int rg = 0; rg < 4; rg++) {
                float v = (acc[i][j][rg] + bv) * scale;
                outbase[(size_t)proj * (4096 * 1024) + (size_t)(row0 + rg) * HSZ + colo] = f2bf(v);
            }
        }
    }
}

// ---------------------------------------------------------------------------
// Output GEMM: fp32 out, BM=64 x BN=128 tiles -> 512 blocks (2/CU).
// ---------------------------------------------------------------------------
__global__ __launch_bounds__(256) void gemm_o64_kernel(
    const unsigned short* __restrict__ A, const unsigned short* __restrict__ B,
    const float* __restrict__ bias, float* __restrict__ out)
{
    __shared__ __align__(16) unsigned short As[2][2048];
    __shared__ __align__(16) unsigned short Bs[2][4096];

    int raw = blockIdx.x;
    int xcd = raw & 7, idx = raw >> 3;       // idx in [0,64)
    int mb = (xcd * 8 + (idx & 7)) * 64;     // 8 mb-slabs per XCD
    int nb = (idx >> 3) * 128;

    int t = threadIdx.x;
    int lane = t & 63, w = t >> 6;
    int lr = lane & 15, lg = lane >> 4;
    int wm = (w >> 1) * 32, wn = (w & 1) * 64;

    int c0 = w * 64 + lane;
    int r0 = c0 >> 2, e0 = (c0 & 3) * 8;
    const unsigned short* gA0 = A + (size_t)(mb + r0) * HSZ + e0;
    const unsigned short* gB0 = B + (size_t)(nb + r0) * HSZ + e0;
    const unsigned short* gB1 = B + (size_t)(nb + r0 + 64) * HSZ + e0;

    f32x4 acc[2][4] = {};

    auto stage = [&](int buf, int kt) {
        gload_lds16(gA0 + kt, &As[buf][w * 512]);
        gload_lds16(gB0 + kt, &Bs[buf][w * 512]);
        gload_lds16(gB1 + kt, &Bs[buf][2048 + w * 512]);
    };

    stage(0, 0);
    __syncthreads();

    int buf = 0;
    for (int kt = 0; kt < HSZ; kt += 32) {
        if (kt + 32 < HSZ) stage(buf ^ 1, kt + 32);

        short8v af[2], bfv[4];
#pragma unroll
        for (int s = 0; s < 2; s++)
            af[s]  = *(const short8v*)&As[buf][(wm + s * 16 + lr) * 32 + lg * 8];
#pragma unroll
        for (int s = 0; s < 4; s++)
            bfv[s] = *(const short8v*)&Bs[buf][(wn + s * 16 + lr) * 32 + lg * 8];
#pragma unroll
        for (int i = 0; i < 2; i++)
#pragma unroll
            for (int j = 0; j < 4; j++)
                acc[i][j] = __builtin_amdgcn_mfma_f32_16x16x32_bf16(af[i], bfv[j], acc[i][j], 0, 0, 0);
        __syncthreads();
        buf ^= 1;
    }

#pragma unroll
    for (int j = 0; j < 4; j++) {
        int colo = nb + wn + j * 16 + lr;
        float bv = bias[colo];
#pragma unroll
        for (int i = 0; i < 2; i++) {
            int row0 = mb + wm + i * 16 + lg * 4;
#pragma unroll
            for (int rg = 0; rg < 4; rg++)
                out[(size_t)(row0 + rg) * HSZ + colo] = acc[i][j][rg] + bv;
        }
    }
}

// ---------------------------------------------------------------------------
// Legacy fp32-A GEMM (fallback path if ws is small).
// ---------------------------------------------------------------------------
template<bool ABF16, bool OUTBF16>
__global__ __launch_bounds__(256) void gemm_bt_kernel(
    const void* __restrict__ Aptr, const unsigned short* __restrict__ Bt,
    const float* __restrict__ bias, float scale, void* __restrict__ outp)
{
    __shared__ __align__(16) unsigned short As[128][40];
    __shared__ __align__(16) unsigned short Bs[128][40];

    int t = threadIdx.x;
    int lane = t & 63, w = t >> 6;
    int lr = lane & 15, lg = lane >> 4;
    int mb = blockIdx.y * 128, nb = blockIdx.x * 128;
    int wm = (w >> 1) * 64, wn = (w & 1) * 64;
    int r = t >> 1, cc = (t & 1) * 16;

    f32x4 acc[4][4] = {};

    for (int kt = 0; kt < HSZ; kt += 32) {
        if (ABF16) {
            const unsigned short* A = (const unsigned short*)Aptr + (size_t)(mb + r) * HSZ + kt + cc;
            *(uint4*)&As[r][cc]     = ((const uint4*)A)[0];
            *(uint4*)&As[r][cc + 8] = ((const uint4*)A)[1];
        } else {
            const float* A = (const float*)Aptr + (size_t)(mb + r) * HSZ + kt + cc;
            unsigned short tmp[16];
#pragma unroll
            for (int q = 0; q < 4; q++) {
                float4 v = ((const float4*)A)[q];
                tmp[q * 4 + 0] = f2bf(v.x); tmp[q * 4 + 1] = f2bf(v.y);
                tmp[q * 4 + 2] = f2bf(v.z); tmp[q * 4 + 3] = f2bf(v.w);
            }
            *(uint4*)&As[r][cc]     = *(uint4*)&tmp[0];
            *(uint4*)&As[r][cc + 8] = *(uint4*)&tmp[8];
        }
        {
            const unsigned short* B = Bt + (size_t)(nb + r) * HSZ + kt + cc;
            *(uint4*)&Bs[r][cc]     = ((const uint4*)B)[0];
            *(uint4*)&Bs[r][cc + 8] = ((const uint4*)B)[1];
        }
        __syncthreads();

        short8v af[4], bf[4];
#pragma unroll
        for (int s = 0; s < 4; s++) af[s] = *(const short8v*)&As[wm + s * 16 + lr][8 * lg];
#pragma unroll
        for (int s = 0; s < 4; s++) bf[s] = *(const short8v*)&Bs[wn + s * 16 + lr][8 * lg];
#pragma unroll
        for (int i = 0; i < 4; i++)
#pragma unroll
            for (int j = 0; j < 4; j++)
                acc[i][j] = __builtin_amdgcn_mfma_f32_16x16x32_bf16(af[i], bf[j], acc[i][j], 0, 0, 0);
        __syncthreads();
    }

#pragma unroll
    for (int j = 0; j < 4; j++) {
        int col = nb + wn + j * 16 + lr;
        float bv = bias[col];
#pragma unroll
        for (int i = 0; i < 4; i++) {
            int row0 = mb + wm + i * 16 + lg * 4;
#pragma unroll
            for (int rg = 0; rg < 4; rg++) {
                float v = (acc[i][j][rg] + bv) * scale;
                if (OUTBF16)
                    ((unsigned short*)outp)[(size_t)(row0 + rg) * HSZ + col] = f2bf(v);
                else
                    ((float*)outp)[(size_t)(row0 + rg) * HSZ + col] = v;
            }
        }
    }
}

// ---------------------------------------------------------------------------
// Phase 1 (uniform chunks): Csum[head][j] += sum over i-chunk of exp(S_ij).
// Grid 4096: (xcd, head, jbi, chunk c of 512 rows). Chunks entirely above
// the diagonal exit early. Uniform 8 iterations/wave -> 16 blocks/CU with
// refill; atomicAdd merges partials (device-scope, <=4 adds/column).
// ---------------------------------------------------------------------------
__global__ __launch_bounds__(256) void colsum_kernel(
    const unsigned short* __restrict__ Qb, const unsigned short* __restrict__ Kb,
    float* __restrict__ Csum)
{
    int raw = blockIdx.x;
    int xcd = raw & 7, idx = raw >> 3;        // idx in [0,512)
    int head = xcd * 4 + (idx >> 7);          // 4 heads per XCD
    int rem = idx & 127;
    int jbi = rem >> 2, c = rem & 3;          // 32 col-blocks x 4 chunks
    if (c < (jbi >> 3)) return;               // chunk entirely above diagonal
    int jb = jbi * 64;
    const unsigned short* Qh = Qb + (size_t)head * L * HDIM;
    const unsigned short* Kh = Kb + (size_t)head * L * HDIM;
    int t = threadIdx.x, lane = t & 63, w = t >> 6;
    int lr = lane & 15, lg = lane >> 4;

    short8v af[4][2];
#pragma unroll
    for (int sj = 0; sj < 4; sj++)
#pragma unroll
        for (int kk = 0; kk < 2; kk++)
            af[sj][kk] = *(const short8v*)&Kh[(size_t)(jb + sj * 16 + lr) * HDIM + kk * 32 + 8 * lg];

    float accs[4][4] = {};
    int base = c * 512 + w * 16;

    for (int k = 0; k < 8; ++k) {
        int it = base + k * 64;
        if (it + 16 <= jb) continue;          // rows entirely above diagonal
        short8v bc0 = *(const short8v*)&Qh[(size_t)(it + lr) * HDIM + 8 * lg];
        short8v bc1 = *(const short8v*)&Qh[(size_t)(it + lr) * HDIM + 32 + 8 * lg];
        if (it >= jb + 64) {                  // interior: unmasked
#pragma unroll
            for (int sj = 0; sj < 4; sj++) {
                f32x4 d = {0.0f, 0.0f, 0.0f, 0.0f};
                d = __builtin_amdgcn_mfma_f32_16x16x32_bf16(af[sj][0], bc0, d, 0, 0, 0);
                d = __builtin_amdgcn_mfma_f32_16x16x32_bf16(af[sj][1], bc1, d, 0, 0, 0);
#pragma unroll
                for (int rg = 0; rg < 4; rg++)
                    accs[sj][rg] += __expf(d[rg]);
            }
        } else {                              // diagonal overlap: masked
            int i = it + lr;
#pragma unroll
            for (int sj = 0; sj < 4; sj++) {
                f32x4 d = {0.0f, 0.0f, 0.0f, 0.0f};
                d = __builtin_amdgcn_mfma_f32_16x16x32_bf16(af[sj][0], bc0, d, 0, 0, 0);
                d = __builtin_amdgcn_mfma_f32_16x16x32_bf16(af[sj][1], bc1, d, 0, 0, 0);
#pragma unroll
                for (int rg = 0; rg < 4; rg++) {
                    int j = jb + sj * 16 + lg * 4 + rg;
                    if (i >= j) accs[sj][rg] += __expf(d[rg]);
                }
            }
        }
    }

    __shared__ float part[4][64];
#pragma unroll
    for (int sj = 0; sj < 4; sj++)
#pragma unroll
        for (int rg = 0; rg < 4; rg++) {
            float v = accs[sj][rg];
            v += __shfl_xor(v, 1); v += __shfl_xor(v, 2);
            v += __shfl_xor(v, 4); v += __shfl_xor(v, 8);
            if (lr == 0) part[w][sj * 16 + lg * 4 + rg] = v;
        }
    __syncthreads();
    if (t < 64) {
        float s = part[0][t] + part[1][t] + part[2][t] + part[3][t];
        atomicAdd(&Csum[(size_t)head * L + jb + t], s);
    }
}

// ---------------------------------------------------------------------------
// V transpose with 1/Csum folded: Vt[p][c][j] = bf16(V[p][j][c] / Csum[p][j]).
// ---------------------------------------------------------------------------
__global__ __launch_bounds__(256) void vtrans_kernel(
    const unsigned short* __restrict__ Vb, const float* __restrict__ Csum,
    unsigned short* __restrict__ Vt)
{
    int p = blockIdx.y;
    int j0 = blockIdx.x * 64;
    const unsigned short* Vp = Vb + (size_t)p * L * HDIM;
    unsigned short* Tp = Vt + (size_t)p * HDIM * L;
    __shared__ __align__(16) unsigned short tl[64][72];
    int t = threadIdx.x;
    int jl = t >> 2, c0 = (t & 3) * 16;
    float rcv = 1.0f / Csum[(size_t)p * L + j0 + jl];
    const unsigned short* src = Vp + (size_t)(j0 + jl) * HDIM + c0;
    unsigned short raw[16];
    *(uint4*)&raw[0] = ((const uint4*)src)[0];
    *(uint4*)&raw[8] = ((const uint4*)src)[1];
#pragma unroll
    for (int e = 0; e < 16; e++) tl[jl][c0 + e] = f2bf(bf2f(raw[e]) * rcv);
    __syncthreads();
    int cl = t >> 2, jc = (t & 3) * 16;
    unsigned short tmp[16];
#pragma unroll
    for (int e = 0; e < 16; e++) tmp[e] = tl[jc + e][cl];
    unsigned short* dst = Tp + (size_t)cl * L + j0 + jc;
    ((uint4*)dst)[0] = *(uint4*)&tmp[0];
    ((uint4*)dst)[1] = *(uint4*)&tmp[8];
}

// ---------------------------------------------------------------------------
// Phase 2 (LDS-staged flash loop, 8 waves): block covers 128 q-rows.
// EXACT R9 version (proven): complementary pairing via idx bit5 XOR into
// snake parity; diagonal-only masking; XOR-swizzled dbuf LDS staging.
// ---------------------------------------------------------------------------
__global__ __launch_bounds__(512) void attn_kernel(
    const unsigned short* __restrict__ Qb, const unsigned short* __restrict__ Kb,
    const unsigned short* __restrict__ Vtg, unsigned short* __restrict__ Ctx)
{
    int raw = blockIdx.x;
    int xcd = raw & 7, idx = raw >> 3;            // idx in [0,64)
    int head = xcd * 4 + (idx >> 4);              // 4 heads per XCD
    int jpos = (idx & 15) ^ ((idx >> 5) & 1);     // complementary per co-resident pair
    int qtile = (jpos & 1) ? (jpos >> 1) : (15 - (jpos >> 1));   // snake
    int qb = qtile * 128;
    int nt = qb / 64 + 2;                          // KV tiles this block touches

    const unsigned short* Qh = Qb + (size_t)head * L * HDIM;
    const unsigned short* Kh = Kb + (size_t)head * L * HDIM;
    const unsigned short* Vh = Vtg + (size_t)head * HDIM * L;   // [64][2048]
    unsigned short* Ch = Ctx + (size_t)head * L * HDIM;

    int t = threadIdx.x;
    int lane = t & 63, w = t >> 6;
    int ws = w & 3;                                // strip
    int w2 = w >> 2;                               // which 32-j window
    int lr = lane & 15, lg = lane >> 4;
    int iw = qb + ws * 32;
    int src0 = ((lane & 16) << 1) + lr;
    int src1 = src0 + 16;
    bool jlow = (lg < 2);

    // SMEM[0..1] = Kt dbuf, SMEM[2..3] = Vl dbuf; reused as f32x4 dump at end
    __shared__ __align__(16) unsigned short SMEM[4][4096];

    int srow = ws * 8 + (lane >> 3);
    int soff = ((lane & 7) ^ (lane >> 3)) * 8;     // pre-XORed source offset

    auto stageT = [&](int buf, int jt) {
        if (w < 4) {
            gload_lds16(Kh + (size_t)(jt + srow) * HDIM + soff,      &SMEM[buf][ws * 512]);
            gload_lds16(Kh + (size_t)(jt + srow + 32) * HDIM + soff, &SMEM[buf][ws * 512 + 2048]);
        } else {
            gload_lds16(Vh + (size_t)srow * L + jt + soff,           &SMEM[2 + buf][ws * 512]);
            gload_lds16(Vh + (size_t)(srow + 32) * L + jt + soff,    &SMEM[2 + buf][ws * 512 + 2048]);
        }
    };

    short8v bq[2][2];
#pragma unroll
    for (int isub = 0; isub < 2; isub++)
#pragma unroll
        for (int kd = 0; kd < 2; kd++)
            bq[isub][kd] = *(const short8v*)&Qh[(size_t)(iw + isub * 16 + lr) * HDIM + kd * 32 + 8 * lg];

    f32x4 acc[4][2] = {};   // ctx^T [csub][isub]: D(c=lg*4+rg, i=lr)

    stageT(0, 0);
    __syncthreads();

    for (int tt = 0; tt < nt; ++tt) {
        int buf = tt & 1;
        if (tt + 1 < nt) stageT(buf ^ 1, (tt + 1) * 64);

        int jt32 = tt * 64 + w2 * 32;
        if (jt32 <= iw + 31) {
            short8v ak[2][2];
#pragma unroll
            for (int jsub = 0; jsub < 2; jsub++)
#pragma unroll
                for (int kd = 0; kd < 2; kd++) {
                    int lrow = w2 * 32 + jsub * 16 + lr;
                    int off = lrow * 64 + ((((kd << 2) | lg) ^ (lr & 7)) << 3);
                    ak[jsub][kd] = *(const short8v*)&SMEM[buf][off];
                }
            short8v av[4];
#pragma unroll
            for (int csub = 0; csub < 4; csub++) {
                int vrow = csub * 16 + lr;
                int off = vrow * 64 + ((((w2 << 2) | lg) ^ (lr & 7)) << 3);
                av[csub] = *(const short8v*)&SMEM[2 + buf][off];
            }

            unsigned int pk[2][2][2];   // [jsub][isub][word]
            if (jt32 == iw) {           // the single diagonal window: masked
#pragma unroll
                for (int jsub = 0; jsub < 2; jsub++)
#pragma unroll
                    for (int isub = 0; isub < 2; isub++) {
                        f32x4 s = {0.0f, 0.0f, 0.0f, 0.0f};
                        s = __builtin_amdgcn_mfma_f32_16x16x32_bf16(ak[jsub][0], bq[isub][0], s, 0, 0, 0);
                        s = __builtin_amdgcn_mfma_f32_16x16x32_bf16(ak[jsub][1], bq[isub][1], s, 0, 0, 0);
                        int i = iw + isub * 16 + lr;
                        int jb0 = jt32 + jsub * 16 + lg * 4;
                        float p[4];
#pragma unroll
                        for (int rg = 0; rg < 4; rg++)
                            p[rg] = (jb0 + rg <= i) ? __expf(s[rg]) : 0.0f;
                        pk[jsub][isub][0] = cvt_pk_bf16(p[0], p[1]);
                        pk[jsub][isub][1] = cvt_pk_bf16(p[2], p[3]);
                    }
            } else {                    // interior: j < iw <= i, no mask
#pragma unroll
                for (int jsub = 0; jsub < 2; jsub++)
#pragma unroll
                    for (int isub = 0; isub < 2; isub++) {
                        f32x4 s = {0.0f, 0.0f, 0.0f, 0.0f};
                        s = __builtin_amdgcn_mfma_f32_16x16x32_bf16(ak[jsub][0], bq[isub][0], s, 0, 0, 0);
                        s = __builtin_amdgcn_mfma_f32_16x16x32_bf16(ak[jsub][1], bq[isub][1], s, 0, 0, 0);
                        pk[jsub][isub][0] = cvt_pk_bf16(__expf(s[0]), __expf(s[1]));
                        pk[jsub][isub][1] = cvt_pk_bf16(__expf(s[2]), __expf(s[3]));
                    }
            }
            __builtin_amdgcn_s_setprio(1);
#pragma unroll
            for (int isub = 0; isub < 2; isub++) {
                int a0 = __shfl((int)pk[0][isub][0], src0);
                int a1 = __shfl((int)pk[0][isub][1], src0);
                int a2 = __shfl((int)pk[0][isub][0], src1);
                int a3 = __shfl((int)pk[0][isub][1], src1);
                int b0 = __shfl((int)pk[1][isub][0], src0);
                int b1 = __shfl((int)pk[1][isub][1], src0);
                int b2 = __shfl((int)pk[1][isub][0], src1);
                int b3 = __shfl((int)pk[1][isub][1], src1);
                int4 wvv;
                wvv.x = jlow ? a0 : b0;
                wvv.y = jlow ? a1 : b1;
                wvv.z = jlow ? a2 : b2;
                wvv.w = jlow ? a3 : b3;
                short8v bp = __builtin_bit_cast(short8v, wvv);
#pragma unroll
                for (int csub = 0; csub < 4; csub++)
                    acc[csub][isub] = __builtin_amdgcn_mfma_f32_16x16x32_bf16(av[csub], bp, acc[csub][isub], 0, 0, 0);
            }
            __builtin_amdgcn_s_setprio(0);
        }
        __syncthreads();   // stage(t+1) drained + all reads of buf done
    }

    // cross-wave pair reduction: waves 4-7 dump acc to LDS, waves 0-3 add+store
    uint4* red = (uint4*)SMEM;   // 2048 uint4 = 32 KB
    if (w >= 4) {
#pragma unroll
        for (int csub = 0; csub < 4; csub++)
#pragma unroll
            for (int isub = 0; isub < 2; isub++)
                red[((ws * 8) + csub * 2 + isub) * 64 + lane] =
                    __builtin_bit_cast(uint4, acc[csub][isub]);
    }
    __syncthreads();
    if (w < 4) {
#pragma unroll
        for (int csub = 0; csub < 4; csub++)
#pragma unroll
            for (int isub = 0; isub < 2; isub++)
                acc[csub][isub] += __builtin_bit_cast(f32x4,
                    red[((ws * 8) + csub * 2 + isub) * 64 + lane]);

#pragma unroll
        for (int csub = 0; csub < 4; csub++)
#pragma unroll
            for (int isub = 0; isub < 2; isub++) {
                int i = iw + isub * 16 + lr;
                int c0 = csub * 16 + lg * 4;
                unsigned short t4[4];
#pragma unroll
                for (int rg = 0; rg < 4; rg++) t4[rg] = f2bf(acc[csub][isub][rg]);
                *(uint2*)&Ch[(size_t)i * HDIM + c0] = *(uint2*)t4;
            }
    }
}

// ---------------------------------------------------------------------------
extern "C" void kernel_launch(void* const* d_in, const int* in_sizes, int n_in,
                              void* d_out, int out_size, void* d_ws, size_t ws_size,
                              hipStream_t stream)
{
    const float* H_q = (const float*)d_in[0];
    const float* H_k = (const float*)d_in[1];
    const float* H_v = (const float*)d_in[2];
    const float* W_q = (const float*)d_in[3];
    const float* b_q = (const float*)d_in[4];
    const float* W_k = (const float*)d_in[5];
    const float* b_k = (const float*)d_in[6];
    const float* W_v = (const float*)d_in[7];
    const float* b_v = (const float*)d_in[8];
    const float* W_o = (const float*)d_in[9];
    const float* b_o = (const float*)d_in[10];

    char* ws = (char*)d_ws;
    const size_t MB = (size_t)1 << 20;
    const float scale = 0.03125f;  // 1/sqrt(1024)

    if (ws_size >= 60 * MB) {
        unsigned short* Hbf = (unsigned short*)(ws);
        unsigned short* Vt  = (unsigned short*)(ws);
        unsigned short* Ctx = (unsigned short*)(ws + 8 * MB);
        unsigned short* Wt4 = (unsigned short*)(ws + 24 * MB);
        unsigned short* Qb  = (unsigned short*)(ws + 32 * MB);
        unsigned short* Kb  = (unsigned short*)(ws + 40 * MB);
        unsigned short* Vb  = (unsigned short*)(ws + 48 * MB);
        float* Csum = (float*)(ws + 56 * MB);   // 256 KB

        wtrans_kernel<<<dim3(16, 16, 4), 256, 0, stream>>>(W_q, W_k, W_v, W_o, Wt4);
        hconv_kernel<<<dim3(2048, 3), 256, 0, stream>>>(H_q, H_k, H_v, Hbf);
        hipMemsetAsync(Csum, 0, (size_t)32 * L * sizeof(float), stream);
        gemm_glds_kernel<<<768, 256, 0, stream>>>(
            Hbf, Wt4, b_q, b_k, b_v, scale, 1.0f, Qb);
        colsum_kernel<<<4096, 256, 0, stream>>>(Qb, Kb, Csum);
        vtrans_kernel<<<dim3(32, 32), 256, 0, stream>>>(Vb, Csum, Vt);
        attn_kernel<<<512, 512, 0, stream>>>(Qb, Kb, Vt, Ctx);
        gemm_o64_kernel<<<512, 256, 0, stream>>>(
            Ctx, Wt4 + (size_t)3 * 1024 * 1024, b_o, (float*)d_out);
    } else {
        unsigned short* Qb  = (unsigned short*)(ws + 0 * MB);
        unsigned short* Kb  = (unsigned short*)(ws + 8 * MB);
        unsigned short* Vt  = (unsigned short*)(ws + 16 * MB);
        unsigned short* Vb  = (unsigned short*)(ws + 24 * MB);
        unsigned short* Ctx = (unsigned short*)(ws + 24 * MB);
        unsigned short* Wt4 = (unsigned short*)(ws + 32 * MB);
        float* Csum = (float*)(ws + 40 * MB);

        wtrans_kernel<<<dim3(16, 16, 4), 256, 0, stream>>>(W_q, W_k, W_v, W_o, Wt4);
        hipMemsetAsync(Csum, 0, (size_t)32 * L * sizeof(float), stream);
        gemm_bt_kernel<false, true><<<dim3(8, 32), 256, 0, stream>>>(H_q, Wt4, b_q, scale, Qb);
        gemm_bt_kernel<false, true><<<dim3(8, 32), 256, 0, stream>>>(H_k, Wt4 + (size_t)1024 * 1024, b_k, scale, Kb);
        gemm_bt_kernel<false, true><<<dim3(8, 32), 256, 0, stream>>>(H_v, Wt4 + (size_t)2 * 1024 * 1024, b_v, 1.0f, Vb);
        colsum_kernel<<<4096, 256, 0, stream>>>(Qb, Kb, Csum);
        vtrans_kernel<<<dim3(32, 32), 256, 0, stream>>>(Vb, Csum, Vt);
        attn_kernel<<<512, 512, 0, stream>>>(Qb, Kb, Vt, Ctx);
        gemm_bt_kernel<true, false><<<dim3(8, 32), 256, 0, stream>>>(Ctx, Wt4 + (size_t)3 * 1024 * 1024, b_o, 1.0f, d_out);
    }
}

// Round 13
// 143.398 us; speedup vs baseline: 1.1824x; 1.1824x over previous
//
#include <hip/hip_runtime.h>

#define L 2048
#define HSZ 1024
#define HDIM 64
// 32 head-panels total (N=2 batches x 16 heads), each a contiguous [2048][64]

typedef float f32x4 __attribute__((ext_vector_type(4)));
typedef short short8v __attribute__((ext_vector_type(8)));

static __device__ __forceinline__ unsigned short f2bf(float f) {
    unsigned int u = __builtin_bit_cast(unsigned int, f);
    u += 0x7FFFu + ((u >> 16) & 1u);   // RNE
    return (unsigned short)(u >> 16);
}
static __device__ __forceinline__ float bf2f(unsigned short u) {
    return __builtin_bit_cast(float, (unsigned int)u << 16);
}
static __device__ __forceinline__ unsigned int cvt_pk_bf16(float lo, float hi) {
    unsigned int r;
    asm("v_cvt_pk_bf16_f32 %0, %1, %2" : "=v"(r) : "v"(lo), "v"(hi));
    return r;
}
static __device__ __forceinline__ void gload_lds16(const void* g, void* l) {
    __builtin_amdgcn_global_load_lds(
        (const __attribute__((address_space(1))) unsigned int*)g,
        (__attribute__((address_space(3))) unsigned int*)l, 16, 0, 0);
}

// ---------------------------------------------------------------------------
// Weights: Wt4[z][n][k] = bf16(W_z[k][n]) for z in {q,k,v,o}.
// ---------------------------------------------------------------------------
__global__ __launch_bounds__(256) void wtrans_kernel(
    const float* __restrict__ W0, const float* __restrict__ W1,
    const float* __restrict__ W2, const float* __restrict__ W3,
    unsigned short* __restrict__ Wt4)
{
    const float* W;
    int z = blockIdx.z;
    if (z == 0) W = W0; else if (z == 1) W = W1; else if (z == 2) W = W2; else W = W3;
    unsigned short* T = Wt4 + (size_t)z * HSZ * HSZ;

    __shared__ __align__(16) unsigned short tl[64][72];
    int t = threadIdx.x;
    int k0 = blockIdx.y * 64, n0 = blockIdx.x * 64;

    int kl = t >> 2, nc = (t & 3) * 16;
    const float* src = W + (size_t)(k0 + kl) * HSZ + n0 + nc;
#pragma unroll
    for (int q = 0; q < 4; q++) {
        float4 v = ((const float4*)src)[q];
        tl[kl][nc + q * 4 + 0] = f2bf(v.x);
        tl[kl][nc + q * 4 + 1] = f2bf(v.y);
        tl[kl][nc + q * 4 + 2] = f2bf(v.z);
        tl[kl][nc + q * 4 + 3] = f2bf(v.w);
    }
    __syncthreads();
    int nl = t >> 2, kc = (t & 3) * 16;
    unsigned short tmp[16];
#pragma unroll
    for (int e = 0; e < 16; e++) tmp[e] = tl[kc + e][nl];
    unsigned short* dst = T + (size_t)(n0 + nl) * HSZ + k0 + kc;
    ((uint4*)dst)[0] = *(uint4*)&tmp[0];
    ((uint4*)dst)[1] = *(uint4*)&tmp[8];
}

// ---------------------------------------------------------------------------
// Convert H_q/H_k/H_v fp32 -> bf16 into contiguous Hbf[3][4096][1024].
// ---------------------------------------------------------------------------
__global__ __launch_bounds__(256) void hconv_kernel(
    const float* __restrict__ H0, const float* __restrict__ H1,
    const float* __restrict__ H2, unsigned short* __restrict__ Hbf)
{
    int z = blockIdx.y;
    const float* S = (z == 0) ? H0 : (z == 1) ? H1 : H2;
    size_t base = ((size_t)blockIdx.x * 256 + threadIdx.x) * 8;
    unsigned short* D = Hbf + (size_t)z * (4096 * 1024) + base;
    float4 a = *(const float4*)(S + base);
    float4 b = *(const float4*)(S + base + 4);
    unsigned short o[8] = {f2bf(a.x), f2bf(a.y), f2bf(a.z), f2bf(a.w),
                           f2bf(b.x), f2bf(b.y), f2bf(b.z), f2bf(b.w)};
    *(uint4*)D = *(const uint4*)o;
}

// ---------------------------------------------------------------------------
// QKV GEMM (bf16 out), single-barrier dbuf pipeline, XCD-slab swizzle.
// ---------------------------------------------------------------------------
__global__ __launch_bounds__(256) void gemm_glds_kernel(
    const unsigned short* __restrict__ A, const unsigned short* __restrict__ B,
    const float* __restrict__ bias0, const float* __restrict__ bias1,
    const float* __restrict__ bias2, float scale01, float scale2,
    unsigned short* __restrict__ outbase)
{
    __shared__ __align__(16) unsigned short As[2][4096];
    __shared__ __align__(16) unsigned short Bs[2][4096];

    int raw = blockIdx.x;
    int xcd = raw & 7, idx = raw >> 3;       // idx in [0,96)
    int mb = (xcd * 4 + (idx & 3)) * 128;    // 4 mb-slabs per XCD
    int col = idx >> 2;                      // 0..23
    int proj = col >> 3;
    int nb = (col & 7) * 128;

    int t = threadIdx.x;
    int lane = t & 63, w = t >> 6;
    int lr = lane & 15, lg = lane >> 4;
    int wm = (w >> 1) * 64, wn = (w & 1) * 64;

    const unsigned short* Ap = A + (size_t)proj * (4096 * 1024);
    const unsigned short* Bp = B + (size_t)proj * (1024 * 1024);
    const float* bias = (proj == 0) ? bias0 : (proj == 1) ? bias1 : bias2;
    float scale = (proj < 2) ? scale01 : scale2;

    int c0 = w * 64 + lane;
    int r0 = c0 >> 2, e0 = (c0 & 3) * 8;
    int r1 = r0 + 64;
    const unsigned short* gA0 = Ap + (size_t)(mb + r0) * HSZ + e0;
    const unsigned short* gA1 = Ap + (size_t)(mb + r1) * HSZ + e0;
    const unsigned short* gB0 = Bp + (size_t)(nb + r0) * HSZ + e0;
    const unsigned short* gB1 = Bp + (size_t)(nb + r1) * HSZ + e0;

    f32x4 acc[4][4] = {};

    auto stage = [&](int buf, int kt) {
        gload_lds16(gA0 + kt, &As[buf][w * 512]);
        gload_lds16(gA1 + kt, &As[buf][2048 + w * 512]);
        gload_lds16(gB0 + kt, &Bs[buf][w * 512]);
        gload_lds16(gB1 + kt, &Bs[buf][2048 + w * 512]);
    };

    stage(0, 0);
    __syncthreads();

    int buf = 0;
    for (int kt = 0; kt < HSZ; kt += 32) {
        if (kt + 32 < HSZ) stage(buf ^ 1, kt + 32);

        short8v af[4], bfv[4];
#pragma unroll
        for (int s = 0; s < 4; s++) {
            af[s]  = *(const short8v*)&As[buf][(wm + s * 16 + lr) * 32 + lg * 8];
            bfv[s] = *(const short8v*)&Bs[buf][(wn + s * 16 + lr) * 32 + lg * 8];
        }
#pragma unroll
        for (int i = 0; i < 4; i++)
#pragma unroll
            for (int j = 0; j < 4; j++)
                acc[i][j] = __builtin_amdgcn_mfma_f32_16x16x32_bf16(af[i], bfv[j], acc[i][j], 0, 0, 0);
        __syncthreads();   // drains stage vmcnt + all reads of buf
        buf ^= 1;
    }

#pragma unroll
    for (int j = 0; j < 4; j++) {
        int colo = nb + wn + j * 16 + lr;
        float bv = bias[colo];
#pragma unroll
        for (int i = 0; i < 4; i++) {
            int row0 = mb + wm + i * 16 + lg * 4;
#pragma unroll
            for (int rg = 0; rg < 4; rg++) {
                float v = (acc[i][j][rg] + bv) * scale;
                outbase[(size_t)proj * (4096 * 1024) + (size_t)(row0 + rg) * HSZ + colo] = f2bf(v);
            }
        }
    }
}

// ---------------------------------------------------------------------------
// Output GEMM: fp32 out, BM=64 x BN=128 tiles -> 512 blocks (2/CU).
// ---------------------------------------------------------------------------
__global__ __launch_bounds__(256) void gemm_o64_kernel(
    const unsigned short* __restrict__ A, const unsigned short* __restrict__ B,
    const float* __restrict__ bias, float* __restrict__ out)
{
    __shared__ __align__(16) unsigned short As[2][2048];
    __shared__ __align__(16) unsigned short Bs[2][4096];

    int raw = blockIdx.x;
    int xcd = raw & 7, idx = raw >> 3;       // idx in [0,64)
    int mb = (xcd * 8 + (idx & 7)) * 64;     // 8 mb-slabs per XCD
    int nb = (idx >> 3) * 128;

    int t = threadIdx.x;
    int lane = t & 63, w = t >> 6;
    int lr = lane & 15, lg = lane >> 4;
    int wm = (w >> 1) * 32, wn = (w & 1) * 64;

    int c0 = w * 64 + lane;
    int r0 = c0 >> 2, e0 = (c0 & 3) * 8;
    const unsigned short* gA0 = A + (size_t)(mb + r0) * HSZ + e0;
    const unsigned short* gB0 = B + (size_t)(nb + r0) * HSZ + e0;
    const unsigned short* gB1 = B + (size_t)(nb + r0 + 64) * HSZ + e0;

    f32x4 acc[2][4] = {};

    auto stage = [&](int buf, int kt) {
        gload_lds16(gA0 + kt, &As[buf][w * 512]);
        gload_lds16(gB0 + kt, &Bs[buf][w * 512]);
        gload_lds16(gB1 + kt, &Bs[buf][2048 + w * 512]);
    };

    stage(0, 0);
    __syncthreads();

    int buf = 0;
    for (int kt = 0; kt < HSZ; kt += 32) {
        if (kt + 32 < HSZ) stage(buf ^ 1, kt + 32);

        short8v af[2], bfv[4];
#pragma unroll
        for (int s = 0; s < 2; s++)
            af[s]  = *(const short8v*)&As[buf][(wm + s * 16 + lr) * 32 + lg * 8];
#pragma unroll
        for (int s = 0; s < 4; s++)
            bfv[s] = *(const short8v*)&Bs[buf][(wn + s * 16 + lr) * 32 + lg * 8];
#pragma unroll
        for (int i = 0; i < 2; i++)
#pragma unroll
            for (int j = 0; j < 4; j++)
                acc[i][j] = __builtin_amdgcn_mfma_f32_16x16x32_bf16(af[i], bfv[j], acc[i][j], 0, 0, 0);
        __syncthreads();
        buf ^= 1;
    }

#pragma unroll
    for (int j = 0; j < 4; j++) {
        int colo = nb + wn + j * 16 + lr;
        float bv = bias[colo];
#pragma unroll
        for (int i = 0; i < 2; i++) {
            int row0 = mb + wm + i * 16 + lg * 4;
#pragma unroll
            for (int rg = 0; rg < 4; rg++)
                out[(size_t)(row0 + rg) * HSZ + colo] = acc[i][j][rg] + bv;
        }
    }
}

// ---------------------------------------------------------------------------
// Legacy fp32-A GEMM (fallback path if ws is small).
// ---------------------------------------------------------------------------
template<bool ABF16, bool OUTBF16>
__global__ __launch_bounds__(256) void gemm_bt_kernel(
    const void* __restrict__ Aptr, const unsigned short* __restrict__ Bt,
    const float* __restrict__ bias, float scale, void* __restrict__ outp)
{
    __shared__ __align__(16) unsigned short As[128][40];
    __shared__ __align__(16) unsigned short Bs[128][40];

    int t = threadIdx.x;
    int lane = t & 63, w = t >> 6;
    int lr = lane & 15, lg = lane >> 4;
    int mb = blockIdx.y * 128, nb = blockIdx.x * 128;
    int wm = (w >> 1) * 64, wn = (w & 1) * 64;
    int r = t >> 1, cc = (t & 1) * 16;

    f32x4 acc[4][4] = {};

    for (int kt = 0; kt < HSZ; kt += 32) {
        if (ABF16) {
            const unsigned short* A = (const unsigned short*)Aptr + (size_t)(mb + r) * HSZ + kt + cc;
            *(uint4*)&As[r][cc]     = ((const uint4*)A)[0];
            *(uint4*)&As[r][cc + 8] = ((const uint4*)A)[1];
        } else {
            const float* A = (const float*)Aptr + (size_t)(mb + r) * HSZ + kt + cc;
            unsigned short tmp[16];
#pragma unroll
            for (int q = 0; q < 4; q++) {
                float4 v = ((const float4*)A)[q];
                tmp[q * 4 + 0] = f2bf(v.x); tmp[q * 4 + 1] = f2bf(v.y);
                tmp[q * 4 + 2] = f2bf(v.z); tmp[q * 4 + 3] = f2bf(v.w);
            }
            *(uint4*)&As[r][cc]     = *(uint4*)&tmp[0];
            *(uint4*)&As[r][cc + 8] = *(uint4*)&tmp[8];
        }
        {
            const unsigned short* B = Bt + (size_t)(nb + r) * HSZ + kt + cc;
            *(uint4*)&Bs[r][cc]     = ((const uint4*)B)[0];
            *(uint4*)&Bs[r][cc + 8] = ((const uint4*)B)[1];
        }
        __syncthreads();

        short8v af[4], bf[4];
#pragma unroll
        for (int s = 0; s < 4; s++) af[s] = *(const short8v*)&As[wm + s * 16 + lr][8 * lg];
#pragma unroll
        for (int s = 0; s < 4; s++) bf[s] = *(const short8v*)&Bs[wn + s * 16 + lr][8 * lg];
#pragma unroll
        for (int i = 0; i < 4; i++)
#pragma unroll
            for (int j = 0; j < 4; j++)
                acc[i][j] = __builtin_amdgcn_mfma_f32_16x16x32_bf16(af[i], bf[j], acc[i][j], 0, 0, 0);
        __syncthreads();
    }

#pragma unroll
    for (int j = 0; j < 4; j++) {
        int col = nb + wn + j * 16 + lr;
        float bv = bias[col];
#pragma unroll
        for (int i = 0; i < 4; i++) {
            int row0 = mb + wm + i * 16 + lg * 4;
#pragma unroll
            for (int rg = 0; rg < 4; rg++) {
                float v = (acc[i][j][rg] + bv) * scale;
                if (OUTBF16)
                    ((unsigned short*)outp)[(size_t)(row0 + rg) * HSZ + col] = f2bf(v);
                else
                    ((float*)outp)[(size_t)(row0 + rg) * HSZ + col] = v;
            }
        }
    }
}

// ---------------------------------------------------------------------------
// Phase 1 (R9 triangular structure + 2-deep Q prefetch):
// rcpC[head][j] = 1 / sum_{i>=j} exp(S_ij). S^T = mfma(K,Q).
// XCD remap (4 heads/XCD) + complementary jb pairing (co-resident blocks
// alternate jb direction -> constant per-CU work sum). Loads for it+128
// issued while computing it: load->use distance ~2 iters covers L2 latency.
// ---------------------------------------------------------------------------
__global__ __launch_bounds__(256) void colsum_kernel(
    const unsigned short* __restrict__ Qb, const unsigned short* __restrict__ Kb,
    float* __restrict__ rcpC)
{
    int raw = blockIdx.x;
    int xcd = raw & 7, idx = raw >> 3;        // idx in [0,128)
    int head = xcd * 4 + (idx >> 5);          // 4 heads per XCD
    int jbi = idx & 31;
    if ((idx >> 5) & 1) jbi = 31 - jbi;       // complementary per co-resident set
    int jb = jbi * 64;
    const unsigned short* Qh = Qb + (size_t)head * L * HDIM;
    const unsigned short* Kh = Kb + (size_t)head * L * HDIM;
    int t = threadIdx.x, lane = t & 63, w = t >> 6;
    int lr = lane & 15, lg = lane >> 4;

    short8v af[4][2];
#pragma unroll
    for (int sj = 0; sj < 4; sj++)
#pragma unroll
        for (int kk = 0; kk < 2; kk++)
            af[sj][kk] = *(const short8v*)&Kh[(size_t)(jb + sj * 16 + lr) * HDIM + kk * 32 + 8 * lg];

    float accs[4][4] = {};

    int it0 = jb + w * 16;
    // 2-deep prefetch ring: a = current, b = +64, c loaded for +128 in-loop
    short8v a0 = *(const short8v*)&Qh[(size_t)(it0 + lr) * HDIM + 8 * lg];
    short8v a1 = *(const short8v*)&Qh[(size_t)(it0 + lr) * HDIM + 32 + 8 * lg];
    int itB = (it0 + 64 < L) ? it0 + 64 : it0;
    short8v b0 = *(const short8v*)&Qh[(size_t)(itB + lr) * HDIM + 8 * lg];
    short8v b1 = *(const short8v*)&Qh[(size_t)(itB + lr) * HDIM + 32 + 8 * lg];

    for (int it = it0; it < L; it += 64) {
        int itC = (it + 128 < L) ? it + 128 : it;
        short8v cv0 = *(const short8v*)&Qh[(size_t)(itC + lr) * HDIM + 8 * lg];
        short8v cv1 = *(const short8v*)&Qh[(size_t)(itC + lr) * HDIM + 32 + 8 * lg];
        if (it == it0) {   // diagonal-overlap iteration: masked
            int i = it + lr;
#pragma unroll
            for (int sj = 0; sj < 4; sj++) {
                f32x4 d = {0.0f, 0.0f, 0.0f, 0.0f};
                d = __builtin_amdgcn_mfma_f32_16x16x32_bf16(af[sj][0], a0, d, 0, 0, 0);
                d = __builtin_amdgcn_mfma_f32_16x16x32_bf16(af[sj][1], a1, d, 0, 0, 0);
#pragma unroll
                for (int rg = 0; rg < 4; rg++) {
                    int j = jb + sj * 16 + lg * 4 + rg;
                    if (i >= j) accs[sj][rg] += __expf(d[rg]);
                }
            }
        } else {           // interior: i >= jb+64 > jmax, no mask
#pragma unroll
            for (int sj = 0; sj < 4; sj++) {
                f32x4 d = {0.0f, 0.0f, 0.0f, 0.0f};
                d = __builtin_amdgcn_mfma_f32_16x16x32_bf16(af[sj][0], a0, d, 0, 0, 0);
                d = __builtin_amdgcn_mfma_f32_16x16x32_bf16(af[sj][1], a1, d, 0, 0, 0);
#pragma unroll
                for (int rg = 0; rg < 4; rg++)
                    accs[sj][rg] += __expf(d[rg]);
            }
        }
        a0 = b0; a1 = b1; b0 = cv0; b1 = cv1;
    }

    __shared__ float part[4][64];
#pragma unroll
    for (int sj = 0; sj < 4; sj++)
#pragma unroll
        for (int rg = 0; rg < 4; rg++) {
            float v = accs[sj][rg];
            v += __shfl_xor(v, 1); v += __shfl_xor(v, 2);
            v += __shfl_xor(v, 4); v += __shfl_xor(v, 8);
            if (lr == 0) part[w][sj * 16 + lg * 4 + rg] = v;
        }
    __syncthreads();
    if (t < 64) {
        float s = part[0][t] + part[1][t] + part[2][t] + part[3][t];
        rcpC[(size_t)head * L + jb + t] = 1.0f / s;
    }
}

// ---------------------------------------------------------------------------
// V transpose with rcpC folded: Vt[p][c][j] = bf16(V[p][j][c] * rcpC[p][j]).
// ---------------------------------------------------------------------------
__global__ __launch_bounds__(256) void vtrans_kernel(
    const unsigned short* __restrict__ Vb, const float* __restrict__ rcpC,
    unsigned short* __restrict__ Vt)
{
    int p = blockIdx.y;
    int j0 = blockIdx.x * 64;
    const unsigned short* Vp = Vb + (size_t)p * L * HDIM;
    unsigned short* Tp = Vt + (size_t)p * HDIM * L;
    __shared__ __align__(16) unsigned short tl[64][72];
    int t = threadIdx.x;
    int jl = t >> 2, c0 = (t & 3) * 16;
    float rcv = rcpC[(size_t)p * L + j0 + jl];
    const unsigned short* src = Vp + (size_t)(j0 + jl) * HDIM + c0;
    unsigned short raw[16];
    *(uint4*)&raw[0] = ((const uint4*)src)[0];
    *(uint4*)&raw[8] = ((const uint4*)src)[1];
#pragma unroll
    for (int e = 0; e < 16; e++) tl[jl][c0 + e] = f2bf(bf2f(raw[e]) * rcv);
    __syncthreads();
    int cl = t >> 2, jc = (t & 3) * 16;
    unsigned short tmp[16];
#pragma unroll
    for (int e = 0; e < 16; e++) tmp[e] = tl[jc + e][cl];
    unsigned short* dst = Tp + (size_t)cl * L + j0 + jc;
    ((uint4*)dst)[0] = *(uint4*)&tmp[0];
    ((uint4*)dst)[1] = *(uint4*)&tmp[8];
}

// ---------------------------------------------------------------------------
// Phase 2 (LDS-staged flash loop, 8 waves): block covers 128 q-rows.
// EXACT R9 version (proven): complementary pairing via idx bit5 XOR into
// snake parity; diagonal-only masking; XOR-swizzled dbuf LDS staging.
// ---------------------------------------------------------------------------
__global__ __launch_bounds__(512) void attn_kernel(
    const unsigned short* __restrict__ Qb, const unsigned short* __restrict__ Kb,
    const unsigned short* __restrict__ Vtg, unsigned short* __restrict__ Ctx)
{
    int raw = blockIdx.x;
    int xcd = raw & 7, idx = raw >> 3;            // idx in [0,64)
    int head = xcd * 4 + (idx >> 4);              // 4 heads per XCD
    int jpos = (idx & 15) ^ ((idx >> 5) & 1);     // complementary per co-resident pair
    int qtile = (jpos & 1) ? (jpos >> 1) : (15 - (jpos >> 1));   // snake
    int qb = qtile * 128;
    int nt = qb / 64 + 2;                          // KV tiles this block touches

    const unsigned short* Qh = Qb + (size_t)head * L * HDIM;
    const unsigned short* Kh = Kb + (size_t)head * L * HDIM;
    const unsigned short* Vh = Vtg + (size_t)head * HDIM * L;   // [64][2048]
    unsigned short* Ch = Ctx + (size_t)head * L * HDIM;

    int t = threadIdx.x;
    int lane = t & 63, w = t >> 6;
    int ws = w & 3;                                // strip
    int w2 = w >> 2;                               // which 32-j window
    int lr = lane & 15, lg = lane >> 4;
    int iw = qb + ws * 32;
    int src0 = ((lane & 16) << 1) + lr;
    int src1 = src0 + 16;
    bool jlow = (lg < 2);

    // SMEM[0..1] = Kt dbuf, SMEM[2..3] = Vl dbuf; reused as f32x4 dump at end
    __shared__ __align__(16) unsigned short SMEM[4][4096];

    int srow = ws * 8 + (lane >> 3);
    int soff = ((lane & 7) ^ (lane >> 3)) * 8;     // pre-XORed source offset

    auto stageT = [&](int buf, int jt) {
        if (w < 4) {
            gload_lds16(Kh + (size_t)(jt + srow) * HDIM + soff,      &SMEM[buf][ws * 512]);
            gload_lds16(Kh + (size_t)(jt + srow + 32) * HDIM + soff, &SMEM[buf][ws * 512 + 2048]);
        } else {
            gload_lds16(Vh + (size_t)srow * L + jt + soff,           &SMEM[2 + buf][ws * 512]);
            gload_lds16(Vh + (size_t)(srow + 32) * L + jt + soff,    &SMEM[2 + buf][ws * 512 + 2048]);
        }
    };

    short8v bq[2][2];
#pragma unroll
    for (int isub = 0; isub < 2; isub++)
#pragma unroll
        for (int kd = 0; kd < 2; kd++)
            bq[isub][kd] = *(const short8v*)&Qh[(size_t)(iw + isub * 16 + lr) * HDIM + kd * 32 + 8 * lg];

    f32x4 acc[4][2] = {};   // ctx^T [csub][isub]: D(c=lg*4+rg, i=lr)

    stageT(0, 0);
    __syncthreads();

    for (int tt = 0; tt < nt; ++tt) {
        int buf = tt & 1;
        if (tt + 1 < nt) stageT(buf ^ 1, (tt + 1) * 64);

        int jt32 = tt * 64 + w2 * 32;
        if (jt32 <= iw + 31) {
            short8v ak[2][2];
#pragma unroll
            for (int jsub = 0; jsub < 2; jsub++)
#pragma unroll
                for (int kd = 0; kd < 2; kd++) {
                    int lrow = w2 * 32 + jsub * 16 + lr;
                    int off = lrow * 64 + ((((kd << 2) | lg) ^ (lr & 7)) << 3);
                    ak[jsub][kd] = *(const short8v*)&SMEM[buf][off];
                }
            short8v av[4];
#pragma unroll
            for (int csub = 0; csub < 4; csub++) {
                int vrow = csub * 16 + lr;
                int off = vrow * 64 + ((((w2 << 2) | lg) ^ (lr & 7)) << 3);
                av[csub] = *(const short8v*)&SMEM[2 + buf][off];
            }

            unsigned int pk[2][2][2];   // [jsub][isub][word]
            if (jt32 == iw) {           // the single diagonal window: masked
#pragma unroll
                for (int jsub = 0; jsub < 2; jsub++)
#pragma unroll
                    for (int isub = 0; isub < 2; isub++) {
                        f32x4 s = {0.0f, 0.0f, 0.0f, 0.0f};
                        s = __builtin_amdgcn_mfma_f32_16x16x32_bf16(ak[jsub][0], bq[isub][0], s, 0, 0, 0);
                        s = __builtin_amdgcn_mfma_f32_16x16x32_bf16(ak[jsub][1], bq[isub][1], s, 0, 0, 0);
                        int i = iw + isub * 16 + lr;
                        int jb0 = jt32 + jsub * 16 + lg * 4;
                        float p[4];
#pragma unroll
                        for (int rg = 0; rg < 4; rg++)
                            p[rg] = (jb0 + rg <= i) ? __expf(s[rg]) : 0.0f;
                        pk[jsub][isub][0] = cvt_pk_bf16(p[0], p[1]);
                        pk[jsub][isub][1] = cvt_pk_bf16(p[2], p[3]);
                    }
            } else {                    // interior: j < iw <= i, no mask
#pragma unroll
                for (int jsub = 0; jsub < 2; jsub++)
#pragma unroll
                    for (int isub = 0; isub < 2; isub++) {
                        f32x4 s = {0.0f, 0.0f, 0.0f, 0.0f};
                        s = __builtin_amdgcn_mfma_f32_16x16x32_bf16(ak[jsub][0], bq[isub][0], s, 0, 0, 0);
                        s = __builtin_amdgcn_mfma_f32_16x16x32_bf16(ak[jsub][1], bq[isub][1], s, 0, 0, 0);
                        pk[jsub][isub][0] = cvt_pk_bf16(__expf(s[0]), __expf(s[1]));
                        pk[jsub][isub][1] = cvt_pk_bf16(__expf(s[2]), __expf(s[3]));
                    }
            }
            __builtin_amdgcn_s_setprio(1);
#pragma unroll
            for (int isub = 0; isub < 2; isub++) {
                int a0 = __shfl((int)pk[0][isub][0], src0);
                int a1 = __shfl((int)pk[0][isub][1], src0);
                int a2 = __shfl((int)pk[0][isub][0], src1);
                int a3 = __shfl((int)pk[0][isub][1], src1);
                int b0 = __shfl((int)pk[1][isub][0], src0);
                int b1 = __shfl((int)pk[1][isub][1], src0);
                int b2 = __shfl((int)pk[1][isub][0], src1);
                int b3 = __shfl((int)pk[1][isub][1], src1);
                int4 wvv;
                wvv.x = jlow ? a0 : b0;
                wvv.y = jlow ? a1 : b1;
                wvv.z = jlow ? a2 : b2;
                wvv.w = jlow ? a3 : b3;
                short8v bp = __builtin_bit_cast(short8v, wvv);
#pragma unroll
                for (int csub = 0; csub < 4; csub++)
                    acc[csub][isub] = __builtin_amdgcn_mfma_f32_16x16x32_bf16(av[csub], bp, acc[csub][isub], 0, 0, 0);
            }
            __builtin_amdgcn_s_setprio(0);
        }
        __syncthreads();   // stage(t+1) drained + all reads of buf done
    }

    // cross-wave pair reduction: waves 4-7 dump acc to LDS, waves 0-3 add+store
    uint4* red = (uint4*)SMEM;   // 2048 uint4 = 32 KB
    if (w >= 4) {
#pragma unroll
        for (int csub = 0; csub < 4; csub++)
#pragma unroll
            for (int isub = 0; isub < 2; isub++)
                red[((ws * 8) + csub * 2 + isub) * 64 + lane] =
                    __builtin_bit_cast(uint4, acc[csub][isub]);
    }
    __syncthreads();
    if (w < 4) {
#pragma unroll
        for (int csub = 0; csub < 4; csub++)
#pragma unroll
            for (int isub = 0; isub < 2; isub++)
                acc[csub][isub] += __builtin_bit_cast(f32x4,
                    red[((ws * 8) + csub * 2 + isub) * 64 + lane]);

#pragma unroll
        for (int csub = 0; csub < 4; csub++)
#pragma unroll
            for (int isub = 0; isub < 2; isub++) {
                int i = iw + isub * 16 + lr;
                int c0 = csub * 16 + lg * 4;
                unsigned short t4[4];
#pragma unroll
                for (int rg = 0; rg < 4; rg++) t4[rg] = f2bf(acc[csub][isub][rg]);
                *(uint2*)&Ch[(size_t)i * HDIM + c0] = *(uint2*)t4;
            }
    }
}

// ---------------------------------------------------------------------------
extern "C" void kernel_launch(void* const* d_in, const int* in_sizes, int n_in,
                              void* d_out, int out_size, void* d_ws, size_t ws_size,
                              hipStream_t stream)
{
    const float* H_q = (const float*)d_in[0];
    const float* H_k = (const float*)d_in[1];
    const float* H_v = (const float*)d_in[2];
    const float* W_q = (const float*)d_in[3];
    const float* b_q = (const float*)d_in[4];
    const float* W_k = (const float*)d_in[5];
    const float* b_k = (const float*)d_in[6];
    const float* W_v = (const float*)d_in[7];
    const float* b_v = (const float*)d_in[8];
    const float* W_o = (const float*)d_in[9];
    const float* b_o = (const float*)d_in[10];

    char* ws = (char*)d_ws;
    const size_t MB = (size_t)1 << 20;
    const float scale = 0.03125f;  // 1/sqrt(1024)

    if (ws_size >= 60 * MB) {
        unsigned short* Hbf = (unsigned short*)(ws);
        unsigned short* Vt  = (unsigned short*)(ws);
        unsigned short* Ctx = (unsigned short*)(ws + 8 * MB);
        unsigned short* Wt4 = (unsigned short*)(ws + 24 * MB);
        unsigned short* Qb  = (unsigned short*)(ws + 32 * MB);
        unsigned short* Kb  = (unsigned short*)(ws + 40 * MB);
        unsigned short* Vb  = (unsigned short*)(ws + 48 * MB);
        float* rcpC = (float*)(ws + 56 * MB);   // 256 KB

        wtrans_kernel<<<dim3(16, 16, 4), 256, 0, stream>>>(W_q, W_k, W_v, W_o, Wt4);
        hconv_kernel<<<dim3(2048, 3), 256, 0, stream>>>(H_q, H_k, H_v, Hbf);
        gemm_glds_kernel<<<768, 256, 0, stream>>>(
            Hbf, Wt4, b_q, b_k, b_v, scale, 1.0f, Qb);
        colsum_kernel<<<1024, 256, 0, stream>>>(Qb, Kb, rcpC);
        vtrans_kernel<<<dim3(32, 32), 256, 0, stream>>>(Vb, rcpC, Vt);
        attn_kernel<<<512, 512, 0, stream>>>(Qb, Kb, Vt, Ctx);
        gemm_o64_kernel<<<512, 256, 0, stream>>>(
            Ctx, Wt4 + (size_t)3 * 1024 * 1024, b_o, (float*)d_out);
    } else {
        unsigned short* Qb  = (unsigned short*)(ws + 0 * MB);
        unsigned short* Kb  = (unsigned short*)(ws + 8 * MB);
        unsigned short* Vt  = (unsigned short*)(ws + 16 * MB);
        unsigned short* Vb  = (unsigned short*)(ws + 24 * MB);
        unsigned short* Ctx = (unsigned short*)(ws + 24 * MB);
        unsigned short* Wt4 = (unsigned short*)(ws + 32 * MB);
        float* rcpC = (float*)(ws + 40 * MB);

        wtrans_kernel<<<dim3(16, 16, 4), 256, 0, stream>>>(W_q, W_k, W_v, W_o, Wt4);
        gemm_bt_kernel<false, true><<<dim3(8, 32), 256, 0, stream>>>(H_q, Wt4, b_q, scale, Qb);
        gemm_bt_kernel<false, true><<<dim3(8, 32), 256, 0, stream>>>(H_k, Wt4 + (size_t)1024 * 1024, b_k, scale, Kb);
        gemm_bt_kernel<false, true><<<dim3(8, 32), 256, 0, stream>>>(H_v, Wt4 + (size_t)2 * 1024 * 1024, b_v, 1.0f, Vb);
        colsum_kernel<<<1024, 256, 0, stream>>>(Qb, Kb, rcpC);
        vtrans_kernel<<<dim3(32, 32), 256, 0, stream>>>(Vb, rcpC, Vt);
        attn_kernel<<<512, 512, 0, stream>>>(Qb, Kb, Vt, Ctx);
        gemm_bt_kernel<true, false><<<dim3(8, 32), 256, 0, stream>>>(Ctx, Wt4 + (size_t)3 * 1024 * 1024, b_o, 1.0f, d_out);
    }
}

// Round 14
// 142.179 us; speedup vs baseline: 1.1925x; 1.0086x over previous
//
#include <hip/hip_runtime.h>

#define L 2048
#define HSZ 1024
#define HDIM 64
// 32 head-panels total (N=2 batches x 16 heads), each a contiguous [2048][64]

typedef float f32x4 __attribute__((ext_vector_type(4)));
typedef short short8v __attribute__((ext_vector_type(8)));

static __device__ __forceinline__ unsigned short f2bf(float f) {
    unsigned int u = __builtin_bit_cast(unsigned int, f);
    u += 0x7FFFu + ((u >> 16) & 1u);   // RNE
    return (unsigned short)(u >> 16);
}
static __device__ __forceinline__ float bf2f(unsigned short u) {
    return __builtin_bit_cast(float, (unsigned int)u << 16);
}
static __device__ __forceinline__ unsigned int cvt_pk_bf16(float lo, float hi) {
    unsigned int r;
    asm("v_cvt_pk_bf16_f32 %0, %1, %2" : "=v"(r) : "v"(lo), "v"(hi));
    return r;
}
static __device__ __forceinline__ void gload_lds16(const void* g, void* l) {
    __builtin_amdgcn_global_load_lds(
        (const __attribute__((address_space(1))) unsigned int*)g,
        (__attribute__((address_space(3))) unsigned int*)l, 16, 0, 0);
}

// ---------------------------------------------------------------------------
// Weights: Wt4[z][n][k] = bf16(W_z[k][n]) for z in {q,k,v,o}.
// ---------------------------------------------------------------------------
__global__ __launch_bounds__(256) void wtrans_kernel(
    const float* __restrict__ W0, const float* __restrict__ W1,
    const float* __restrict__ W2, const float* __restrict__ W3,
    unsigned short* __restrict__ Wt4)
{
    const float* W;
    int z = blockIdx.z;
    if (z == 0) W = W0; else if (z == 1) W = W1; else if (z == 2) W = W2; else W = W3;
    unsigned short* T = Wt4 + (size_t)z * HSZ * HSZ;

    __shared__ __align__(16) unsigned short tl[64][72];
    int t = threadIdx.x;
    int k0 = blockIdx.y * 64, n0 = blockIdx.x * 64;

    int kl = t >> 2, nc = (t & 3) * 16;
    const float* src = W + (size_t)(k0 + kl) * HSZ + n0 + nc;
#pragma unroll
    for (int q = 0; q < 4; q++) {
        float4 v = ((const float4*)src)[q];
        tl[kl][nc + q * 4 + 0] = f2bf(v.x);
        tl[kl][nc + q * 4 + 1] = f2bf(v.y);
        tl[kl][nc + q * 4 + 2] = f2bf(v.z);
        tl[kl][nc + q * 4 + 3] = f2bf(v.w);
    }
    __syncthreads();
    int nl = t >> 2, kc = (t & 3) * 16;
    unsigned short tmp[16];
#pragma unroll
    for (int e = 0; e < 16; e++) tmp[e] = tl[kc + e][nl];
    unsigned short* dst = T + (size_t)(n0 + nl) * HSZ + k0 + kc;
    ((uint4*)dst)[0] = *(uint4*)&tmp[0];
    ((uint4*)dst)[1] = *(uint4*)&tmp[8];
}

// ---------------------------------------------------------------------------
// Convert H_q/H_k/H_v fp32 -> bf16 into contiguous Hbf[3][4096][1024].
// ---------------------------------------------------------------------------
__global__ __launch_bounds__(256) void hconv_kernel(
    const float* __restrict__ H0, const float* __restrict__ H1,
    const float* __restrict__ H2, unsigned short* __restrict__ Hbf)
{
    int z = blockIdx.y;
    const float* S = (z == 0) ? H0 : (z == 1) ? H1 : H2;
    size_t base = ((size_t)blockIdx.x * 256 + threadIdx.x) * 8;
    unsigned short* D = Hbf + (size_t)z * (4096 * 1024) + base;
    float4 a = *(const float4*)(S + base);
    float4 b = *(const float4*)(S + base + 4);
    unsigned short o[8] = {f2bf(a.x), f2bf(a.y), f2bf(a.z), f2bf(a.w),
                           f2bf(b.x), f2bf(b.y), f2bf(b.z), f2bf(b.w)};
    *(uint4*)D = *(const uint4*)o;
}

// ---------------------------------------------------------------------------
// QKV GEMM (bf16 out), single-barrier dbuf pipeline, XCD-slab swizzle.
// ---------------------------------------------------------------------------
__global__ __launch_bounds__(256) void gemm_glds_kernel(
    const unsigned short* __restrict__ A, const unsigned short* __restrict__ B,
    const float* __restrict__ bias0, const float* __restrict__ bias1,
    const float* __restrict__ bias2, float scale01, float scale2,
    unsigned short* __restrict__ outbase)
{
    __shared__ __align__(16) unsigned short As[2][4096];
    __shared__ __align__(16) unsigned short Bs[2][4096];

    int raw = blockIdx.x;
    int xcd = raw & 7, idx = raw >> 3;       // idx in [0,96)
    int mb = (xcd * 4 + (idx & 3)) * 128;    // 4 mb-slabs per XCD
    int col = idx >> 2;                      // 0..23
    int proj = col >> 3;
    int nb = (col & 7) * 128;

    int t = threadIdx.x;
    int lane = t & 63, w = t >> 6;
    int lr = lane & 15, lg = lane >> 4;
    int wm = (w >> 1) * 64, wn = (w & 1) * 64;

    const unsigned short* Ap = A + (size_t)proj * (4096 * 1024);
    const unsigned short* Bp = B + (size_t)proj * (1024 * 1024);
    const float* bias = (proj == 0) ? bias0 : (proj == 1) ? bias1 : bias2;
    float scale = (proj < 2) ? scale01 : scale2;

    int c0 = w * 64 + lane;
    int r0 = c0 >> 2, e0 = (c0 & 3) * 8;
    int r1 = r0 + 64;
    const unsigned short* gA0 = Ap + (size_t)(mb + r0) * HSZ + e0;
    const unsigned short* gA1 = Ap + (size_t)(mb + r1) * HSZ + e0;
    const unsigned short* gB0 = Bp + (size_t)(nb + r0) * HSZ + e0;
    const unsigned short* gB1 = Bp + (size_t)(nb + r1) * HSZ + e0;

    f32x4 acc[4][4] = {};

    auto stage = [&](int buf, int kt) {
        gload_lds16(gA0 + kt, &As[buf][w * 512]);
        gload_lds16(gA1 + kt, &As[buf][2048 + w * 512]);
        gload_lds16(gB0 + kt, &Bs[buf][w * 512]);
        gload_lds16(gB1 + kt, &Bs[buf][2048 + w * 512]);
    };

    stage(0, 0);
    __syncthreads();

    int buf = 0;
    for (int kt = 0; kt < HSZ; kt += 32) {
        if (kt + 32 < HSZ) stage(buf ^ 1, kt + 32);

        short8v af[4], bfv[4];
#pragma unroll
        for (int s = 0; s < 4; s++) {
            af[s]  = *(const short8v*)&As[buf][(wm + s * 16 + lr) * 32 + lg * 8];
            bfv[s] = *(const short8v*)&Bs[buf][(wn + s * 16 + lr) * 32 + lg * 8];
        }
#pragma unroll
        for (int i = 0; i < 4; i++)
#pragma unroll
            for (int j = 0; j < 4; j++)
                acc[i][j] = __builtin_amdgcn_mfma_f32_16x16x32_bf16(af[i], bfv[j], acc[i][j], 0, 0, 0);
        __syncthreads();   // drains stage vmcnt + all reads of buf
        buf ^= 1;
    }

#pragma unroll
    for (int j = 0; j < 4; j++) {
        int colo = nb + wn + j * 16 + lr;
        float bv = bias[colo];
#pragma unroll
        for (int i = 0; i < 4; i++) {
            int row0 = mb + wm + i * 16 + lg * 4;
#pragma unroll
            for (int rg = 0; rg < 4; rg++) {
                float v = (acc[i][j][rg] + bv) * scale;
                outbase[(size_t)proj * (4096 * 1024) + (size_t)(row0 + rg) * HSZ + colo] = f2bf(v);
            }
        }
    }
}

// ---------------------------------------------------------------------------
// Output GEMM: fp32 out, BM=64 x BN=128 tiles -> 512 blocks (2/CU).
// ---------------------------------------------------------------------------
__global__ __launch_bounds__(256) void gemm_o64_kernel(
    const unsigned short* __restrict__ A, const unsigned short* __restrict__ B,
    const float* __restrict__ bias, float* __restrict__ out)
{
    __shared__ __align__(16) unsigned short As[2][2048];
    __shared__ __align__(16) unsigned short Bs[2][4096];

    int raw = blockIdx.x;
    int xcd = raw & 7, idx = raw >> 3;       // idx in [0,64)
    int mb = (xcd * 8 + (idx & 7)) * 64;     // 8 mb-slabs per XCD
    int nb = (idx >> 3) * 128;

    int t = threadIdx.x;
    int lane = t & 63, w = t >> 6;
    int lr = lane & 15, lg = lane >> 4;
    int wm = (w >> 1) * 32, wn = (w & 1) * 64;

    int c0 = w * 64 + lane;
    int r0 = c0 >> 2, e0 = (c0 & 3) * 8;
    const unsigned short* gA0 = A + (size_t)(mb + r0) * HSZ + e0;
    const unsigned short* gB0 = B + (size_t)(nb + r0) * HSZ + e0;
    const unsigned short* gB1 = B + (size_t)(nb + r0 + 64) * HSZ + e0;

    f32x4 acc[2][4] = {};

    auto stage = [&](int buf, int kt) {
        gload_lds16(gA0 + kt, &As[buf][w * 512]);
        gload_lds16(gB0 + kt, &Bs[buf][w * 512]);
        gload_lds16(gB1 + kt, &Bs[buf][2048 + w * 512]);
    };

    stage(0, 0);
    __syncthreads();

    int buf = 0;
    for (int kt = 0; kt < HSZ; kt += 32) {
        if (kt + 32 < HSZ) stage(buf ^ 1, kt + 32);

        short8v af[2], bfv[4];
#pragma unroll
        for (int s = 0; s < 2; s++)
            af[s]  = *(const short8v*)&As[buf][(wm + s * 16 + lr) * 32 + lg * 8];
#pragma unroll
        for (int s = 0; s < 4; s++)
            bfv[s] = *(const short8v*)&Bs[buf][(wn + s * 16 + lr) * 32 + lg * 8];
#pragma unroll
        for (int i = 0; i < 2; i++)
#pragma unroll
            for (int j = 0; j < 4; j++)
                acc[i][j] = __builtin_amdgcn_mfma_f32_16x16x32_bf16(af[i], bfv[j], acc[i][j], 0, 0, 0);
        __syncthreads();
        buf ^= 1;
    }

#pragma unroll
    for (int j = 0; j < 4; j++) {
        int colo = nb + wn + j * 16 + lr;
        float bv = bias[colo];
#pragma unroll
        for (int i = 0; i < 2; i++) {
            int row0 = mb + wm + i * 16 + lg * 4;
#pragma unroll
            for (int rg = 0; rg < 4; rg++)
                out[(size_t)(row0 + rg) * HSZ + colo] = acc[i][j][rg] + bv;
        }
    }
}

// ---------------------------------------------------------------------------
// Legacy fp32-A GEMM (fallback path if ws is small).
// ---------------------------------------------------------------------------
template<bool ABF16, bool OUTBF16>
__global__ __launch_bounds__(256) void gemm_bt_kernel(
    const void* __restrict__ Aptr, const unsigned short* __restrict__ Bt,
    const float* __restrict__ bias, float scale, void* __restrict__ outp)
{
    __shared__ __align__(16) unsigned short As[128][40];
    __shared__ __align__(16) unsigned short Bs[128][40];

    int t = threadIdx.x;
    int lane = t & 63, w = t >> 6;
    int lr = lane & 15, lg = lane >> 4;
    int mb = blockIdx.y * 128, nb = blockIdx.x * 128;
    int wm = (w >> 1) * 64, wn = (w & 1) * 64;
    int r = t >> 1, cc = (t & 1) * 16;

    f32x4 acc[4][4] = {};

    for (int kt = 0; kt < HSZ; kt += 32) {
        if (ABF16) {
            const unsigned short* A = (const unsigned short*)Aptr + (size_t)(mb + r) * HSZ + kt + cc;
            *(uint4*)&As[r][cc]     = ((const uint4*)A)[0];
            *(uint4*)&As[r][cc + 8] = ((const uint4*)A)[1];
        } else {
            const float* A = (const float*)Aptr + (size_t)(mb + r) * HSZ + kt + cc;
            unsigned short tmp[16];
#pragma unroll
            for (int q = 0; q < 4; q++) {
                float4 v = ((const float4*)A)[q];
                tmp[q * 4 + 0] = f2bf(v.x); tmp[q * 4 + 1] = f2bf(v.y);
                tmp[q * 4 + 2] = f2bf(v.z); tmp[q * 4 + 3] = f2bf(v.w);
            }
            *(uint4*)&As[r][cc]     = *(uint4*)&tmp[0];
            *(uint4*)&As[r][cc + 8] = *(uint4*)&tmp[8];
        }
        {
            const unsigned short* B = Bt + (size_t)(nb + r) * HSZ + kt + cc;
            *(uint4*)&Bs[r][cc]     = ((const uint4*)B)[0];
            *(uint4*)&Bs[r][cc + 8] = ((const uint4*)B)[1];
        }
        __syncthreads();

        short8v af[4], bf[4];
#pragma unroll
        for (int s = 0; s < 4; s++) af[s] = *(const short8v*)&As[wm + s * 16 + lr][8 * lg];
#pragma unroll
        for (int s = 0; s < 4; s++) bf[s] = *(const short8v*)&Bs[wn + s * 16 + lr][8 * lg];
#pragma unroll
        for (int i = 0; i < 4; i++)
#pragma unroll
            for (int j = 0; j < 4; j++)
                acc[i][j] = __builtin_amdgcn_mfma_f32_16x16x32_bf16(af[i], bf[j], acc[i][j], 0, 0, 0);
        __syncthreads();
    }

#pragma unroll
    for (int j = 0; j < 4; j++) {
        int col = nb + wn + j * 16 + lr;
        float bv = bias[col];
#pragma unroll
        for (int i = 0; i < 4; i++) {
            int row0 = mb + wm + i * 16 + lg * 4;
#pragma unroll
            for (int rg = 0; rg < 4; rg++) {
                float v = (acc[i][j][rg] + bv) * scale;
                if (OUTBF16)
                    ((unsigned short*)outp)[(size_t)(row0 + rg) * HSZ + col] = f2bf(v);
                else
                    ((float*)outp)[(size_t)(row0 + rg) * HSZ + col] = v;
            }
        }
    }
}

// ---------------------------------------------------------------------------
// Phase 1 FUSED (colsum + vtrans): block (head, jb) computes
// rcpC[jb..jb+63] = 1/sum_{i>=j} exp(S_ij) (R13-proven body, 2-deep
// prefetch), broadcasts it via LDS, then transposes V[jb..jb+63] with the
// fold: Vt[head][c][j] = bf16(V[head][j][c] * rcpC[j]).  Same index space
// as the old vtrans grid (bijective), one launch fewer, no global rcpC.
// ---------------------------------------------------------------------------
__global__ __launch_bounds__(256) void colsum_kernel(
    const unsigned short* __restrict__ Qb, const unsigned short* __restrict__ Kb,
    const unsigned short* __restrict__ Vb, unsigned short* __restrict__ Vt)
{
    int raw = blockIdx.x;
    int xcd = raw & 7, idx = raw >> 3;        // idx in [0,128)
    int head = xcd * 4 + (idx >> 5);          // 4 heads per XCD
    int jbi = idx & 31;
    if ((idx >> 5) & 1) jbi = 31 - jbi;       // complementary per co-resident set
    int jb = jbi * 64;
    const unsigned short* Qh = Qb + (size_t)head * L * HDIM;
    const unsigned short* Kh = Kb + (size_t)head * L * HDIM;
    int t = threadIdx.x, lane = t & 63, w = t >> 6;
    int lr = lane & 15, lg = lane >> 4;

    short8v af[4][2];
#pragma unroll
    for (int sj = 0; sj < 4; sj++)
#pragma unroll
        for (int kk = 0; kk < 2; kk++)
            af[sj][kk] = *(const short8v*)&Kh[(size_t)(jb + sj * 16 + lr) * HDIM + kk * 32 + 8 * lg];

    float accs[4][4] = {};

    int it0 = jb + w * 16;
    // 2-deep prefetch ring: a = current, b = +64, c loaded for +128 in-loop
    short8v a0 = *(const short8v*)&Qh[(size_t)(it0 + lr) * HDIM + 8 * lg];
    short8v a1 = *(const short8v*)&Qh[(size_t)(it0 + lr) * HDIM + 32 + 8 * lg];
    int itB = (it0 + 64 < L) ? it0 + 64 : it0;
    short8v b0 = *(const short8v*)&Qh[(size_t)(itB + lr) * HDIM + 8 * lg];
    short8v b1 = *(const short8v*)&Qh[(size_t)(itB + lr) * HDIM + 32 + 8 * lg];

    for (int it = it0; it < L; it += 64) {
        int itC = (it + 128 < L) ? it + 128 : it;
        short8v cv0 = *(const short8v*)&Qh[(size_t)(itC + lr) * HDIM + 8 * lg];
        short8v cv1 = *(const short8v*)&Qh[(size_t)(itC + lr) * HDIM + 32 + 8 * lg];
        if (it == it0) {   // diagonal-overlap iteration: masked
            int i = it + lr;
#pragma unroll
            for (int sj = 0; sj < 4; sj++) {
                f32x4 d = {0.0f, 0.0f, 0.0f, 0.0f};
                d = __builtin_amdgcn_mfma_f32_16x16x32_bf16(af[sj][0], a0, d, 0, 0, 0);
                d = __builtin_amdgcn_mfma_f32_16x16x32_bf16(af[sj][1], a1, d, 0, 0, 0);
#pragma unroll
                for (int rg = 0; rg < 4; rg++) {
                    int j = jb + sj * 16 + lg * 4 + rg;
                    if (i >= j) accs[sj][rg] += __expf(d[rg]);
                }
            }
        } else {           // interior: i >= jb+64 > jmax, no mask
#pragma unroll
            for (int sj = 0; sj < 4; sj++) {
                f32x4 d = {0.0f, 0.0f, 0.0f, 0.0f};
                d = __builtin_amdgcn_mfma_f32_16x16x32_bf16(af[sj][0], a0, d, 0, 0, 0);
                d = __builtin_amdgcn_mfma_f32_16x16x32_bf16(af[sj][1], a1, d, 0, 0, 0);
#pragma unroll
                for (int rg = 0; rg < 4; rg++)
                    accs[sj][rg] += __expf(d[rg]);
            }
        }
        a0 = b0; a1 = b1; b0 = cv0; b1 = cv1;
    }

    __shared__ float part[4][64];
    __shared__ float rc64[64];
#pragma unroll
    for (int sj = 0; sj < 4; sj++)
#pragma unroll
        for (int rg = 0; rg < 4; rg++) {
            float v = accs[sj][rg];
            v += __shfl_xor(v, 1); v += __shfl_xor(v, 2);
            v += __shfl_xor(v, 4); v += __shfl_xor(v, 8);
            if (lr == 0) part[w][sj * 16 + lg * 4 + rg] = v;
        }
    __syncthreads();
    if (t < 64) {
        float s = part[0][t] + part[1][t] + part[2][t] + part[3][t];
        rc64[t] = 1.0f / s;
    }
    __syncthreads();

    // ---- fused vtrans for this (head, jb): Vt[c][jb+j] = V[jb+j][c]*rc ----
    __shared__ __align__(16) unsigned short tl[64][72];
    const unsigned short* Vp = Vb + (size_t)head * L * HDIM;
    unsigned short* Tp = Vt + (size_t)head * HDIM * L;
    int jl = t >> 2, c0 = (t & 3) * 16;
    float rcv = rc64[jl];
    const unsigned short* src = Vp + (size_t)(jb + jl) * HDIM + c0;
    unsigned short rawv[16];
    *(uint4*)&rawv[0] = ((const uint4*)src)[0];
    *(uint4*)&rawv[8] = ((const uint4*)src)[1];
#pragma unroll
    for (int e = 0; e < 16; e++) tl[jl][c0 + e] = f2bf(bf2f(rawv[e]) * rcv);
    __syncthreads();
    int cl = t >> 2, jc = (t & 3) * 16;
    unsigned short tmp[16];
#pragma unroll
    for (int e = 0; e < 16; e++) tmp[e] = tl[jc + e][cl];
    unsigned short* dst = Tp + (size_t)cl * L + jb + jc;
    ((uint4*)dst)[0] = *(uint4*)&tmp[0];
    ((uint4*)dst)[1] = *(uint4*)&tmp[8];
}

// ---------------------------------------------------------------------------
// Phase 2 (LDS-staged flash loop, 8 waves): block covers 128 q-rows.
// EXACT R9 version (proven): complementary pairing via idx bit5 XOR into
// snake parity; diagonal-only masking; XOR-swizzled dbuf LDS staging.
// ---------------------------------------------------------------------------
__global__ __launch_bounds__(512) void attn_kernel(
    const unsigned short* __restrict__ Qb, const unsigned short* __restrict__ Kb,
    const unsigned short* __restrict__ Vtg, unsigned short* __restrict__ Ctx)
{
    int raw = blockIdx.x;
    int xcd = raw & 7, idx = raw >> 3;            // idx in [0,64)
    int head = xcd * 4 + (idx >> 4);              // 4 heads per XCD
    int jpos = (idx & 15) ^ ((idx >> 5) & 1);     // complementary per co-resident pair
    int qtile = (jpos & 1) ? (jpos >> 1) : (15 - (jpos >> 1));   // snake
    int qb = qtile * 128;
    int nt = qb / 64 + 2;                          // KV tiles this block touches

    const unsigned short* Qh = Qb + (size_t)head * L * HDIM;
    const unsigned short* Kh = Kb + (size_t)head * L * HDIM;
    const unsigned short* Vh = Vtg + (size_t)head * HDIM * L;   // [64][2048]
    unsigned short* Ch = Ctx + (size_t)head * L * HDIM;

    int t = threadIdx.x;
    int lane = t & 63, w = t >> 6;
    int ws = w & 3;                                // strip
    int w2 = w >> 2;                               // which 32-j window
    int lr = lane & 15, lg = lane >> 4;
    int iw = qb + ws * 32;
    int src0 = ((lane & 16) << 1) + lr;
    int src1 = src0 + 16;
    bool jlow = (lg < 2);

    // SMEM[0..1] = Kt dbuf, SMEM[2..3] = Vl dbuf; reused as f32x4 dump at end
    __shared__ __align__(16) unsigned short SMEM[4][4096];

    int srow = ws * 8 + (lane >> 3);
    int soff = ((lane & 7) ^ (lane >> 3)) * 8;     // pre-XORed source offset

    auto stageT = [&](int buf, int jt) {
        if (w < 4) {
            gload_lds16(Kh + (size_t)(jt + srow) * HDIM + soff,      &SMEM[buf][ws * 512]);
            gload_lds16(Kh + (size_t)(jt + srow + 32) * HDIM + soff, &SMEM[buf][ws * 512 + 2048]);
        } else {
            gload_lds16(Vh + (size_t)srow * L + jt + soff,           &SMEM[2 + buf][ws * 512]);
            gload_lds16(Vh + (size_t)(srow + 32) * L + jt + soff,    &SMEM[2 + buf][ws * 512 + 2048]);
        }
    };

    short8v bq[2][2];
#pragma unroll
    for (int isub = 0; isub < 2; isub++)
#pragma unroll
        for (int kd = 0; kd < 2; kd++)
            bq[isub][kd] = *(const short8v*)&Qh[(size_t)(iw + isub * 16 + lr) * HDIM + kd * 32 + 8 * lg];

    f32x4 acc[4][2] = {};   // ctx^T [csub][isub]: D(c=lg*4+rg, i=lr)

    stageT(0, 0);
    __syncthreads();

    for (int tt = 0; tt < nt; ++tt) {
        int buf = tt & 1;
        if (tt + 1 < nt) stageT(buf ^ 1, (tt + 1) * 64);

        int jt32 = tt * 64 + w2 * 32;
        if (jt32 <= iw + 31) {
            short8v ak[2][2];
#pragma unroll
            for (int jsub = 0; jsub < 2; jsub++)
#pragma unroll
                for (int kd = 0; kd < 2; kd++) {
                    int lrow = w2 * 32 + jsub * 16 + lr;
                    int off = lrow * 64 + ((((kd << 2) | lg) ^ (lr & 7)) << 3);
                    ak[jsub][kd] = *(const short8v*)&SMEM[buf][off];
                }
            short8v av[4];
#pragma unroll
            for (int csub = 0; csub < 4; csub++) {
                int vrow = csub * 16 + lr;
                int off = vrow * 64 + ((((w2 << 2) | lg) ^ (lr & 7)) << 3);
                av[csub] = *(const short8v*)&SMEM[2 + buf][off];
            }

            unsigned int pk[2][2][2];   // [jsub][isub][word]
            if (jt32 == iw) {           // the single diagonal window: masked
#pragma unroll
                for (int jsub = 0; jsub < 2; jsub++)
#pragma unroll
                    for (int isub = 0; isub < 2; isub++) {
                        f32x4 s = {0.0f, 0.0f, 0.0f, 0.0f};
                        s = __builtin_amdgcn_mfma_f32_16x16x32_bf16(ak[jsub][0], bq[isub][0], s, 0, 0, 0);
                        s = __builtin_amdgcn_mfma_f32_16x16x32_bf16(ak[jsub][1], bq[isub][1], s, 0, 0, 0);
                        int i = iw + isub * 16 + lr;
                        int jb0 = jt32 + jsub * 16 + lg * 4;
                        float p[4];
#pragma unroll
                        for (int rg = 0; rg < 4; rg++)
                            p[rg] = (jb0 + rg <= i) ? __expf(s[rg]) : 0.0f;
                        pk[jsub][isub][0] = cvt_pk_bf16(p[0], p[1]);
                        pk[jsub][isub][1] = cvt_pk_bf16(p[2], p[3]);
                    }
            } else {                    // interior: j < iw <= i, no mask
#pragma unroll
                for (int jsub = 0; jsub < 2; jsub++)
#pragma unroll
                    for (int isub = 0; isub < 2; isub++) {
                        f32x4 s = {0.0f, 0.0f, 0.0f, 0.0f};
                        s = __builtin_amdgcn_mfma_f32_16x16x32_bf16(ak[jsub][0], bq[isub][0], s, 0, 0, 0);
                        s = __builtin_amdgcn_mfma_f32_16x16x32_bf16(ak[jsub][1], bq[isub][1], s, 0, 0, 0);
                        pk[jsub][isub][0] = cvt_pk_bf16(__expf(s[0]), __expf(s[1]));
                        pk[jsub][isub][1] = cvt_pk_bf16(__expf(s[2]), __expf(s[3]));
                    }
            }
            __builtin_amdgcn_s_setprio(1);
#pragma unroll
            for (int isub = 0; isub < 2; isub++) {
                int a0 = __shfl((int)pk[0][isub][0], src0);
                int a1 = __shfl((int)pk[0][isub][1], src0);
                int a2 = __shfl((int)pk[0][isub][0], src1);
                int a3 = __shfl((int)pk[0][isub][1], src1);
                int b0 = __shfl((int)pk[1][isub][0], src0);
                int b1 = __shfl((int)pk[1][isub][1], src0);
                int b2 = __shfl((int)pk[1][isub][0], src1);
                int b3 = __shfl((int)pk[1][isub][1], src1);
                int4 wvv;
                wvv.x = jlow ? a0 : b0;
                wvv.y = jlow ? a1 : b1;
                wvv.z = jlow ? a2 : b2;
                wvv.w = jlow ? a3 : b3;
                short8v bp = __builtin_bit_cast(short8v, wvv);
#pragma unroll
                for (int csub = 0; csub < 4; csub++)
                    acc[csub][isub] = __builtin_amdgcn_mfma_f32_16x16x32_bf16(av[csub], bp, acc[csub][isub], 0, 0, 0);
            }
            __builtin_amdgcn_s_setprio(0);
        }
        __syncthreads();   // stage(t+1) drained + all reads of buf done
    }

    // cross-wave pair reduction: waves 4-7 dump acc to LDS, waves 0-3 add+store
    uint4* red = (uint4*)SMEM;   // 2048 uint4 = 32 KB
    if (w >= 4) {
#pragma unroll
        for (int csub = 0; csub < 4; csub++)
#pragma unroll
            for (int isub = 0; isub < 2; isub++)
                red[((ws * 8) + csub * 2 + isub) * 64 + lane] =
                    __builtin_bit_cast(uint4, acc[csub][isub]);
    }
    __syncthreads();
    if (w < 4) {
#pragma unroll
        for (int csub = 0; csub < 4; csub++)
#pragma unroll
            for (int isub = 0; isub < 2; isub++)
                acc[csub][isub] += __builtin_bit_cast(f32x4,
                    red[((ws * 8) + csub * 2 + isub) * 64 + lane]);

#pragma unroll
        for (int csub = 0; csub < 4; csub++)
#pragma unroll
            for (int isub = 0; isub < 2; isub++) {
                int i = iw + isub * 16 + lr;
                int c0 = csub * 16 + lg * 4;
                unsigned short t4[4];
#pragma unroll
                for (int rg = 0; rg < 4; rg++) t4[rg] = f2bf(acc[csub][isub][rg]);
                *(uint2*)&Ch[(size_t)i * HDIM + c0] = *(uint2*)t4;
            }
    }
}

// ---------------------------------------------------------------------------
extern "C" void kernel_launch(void* const* d_in, const int* in_sizes, int n_in,
                              void* d_out, int out_size, void* d_ws, size_t ws_size,
                              hipStream_t stream)
{
    const float* H_q = (const float*)d_in[0];
    const float* H_k = (const float*)d_in[1];
    const float* H_v = (const float*)d_in[2];
    const float* W_q = (const float*)d_in[3];
    const float* b_q = (const float*)d_in[4];
    const float* W_k = (const float*)d_in[5];
    const float* b_k = (const float*)d_in[6];
    const float* W_v = (const float*)d_in[7];
    const float* b_v = (const float*)d_in[8];
    const float* W_o = (const float*)d_in[9];
    const float* b_o = (const float*)d_in[10];

    char* ws = (char*)d_ws;
    const size_t MB = (size_t)1 << 20;
    const float scale = 0.03125f;  // 1/sqrt(1024)

    if (ws_size >= 60 * MB) {
        unsigned short* Hbf = (unsigned short*)(ws);
        unsigned short* Vt  = (unsigned short*)(ws);
        unsigned short* Ctx = (unsigned short*)(ws + 8 * MB);
        unsigned short* Wt4 = (unsigned short*)(ws + 24 * MB);
        unsigned short* Qb  = (unsigned short*)(ws + 32 * MB);
        unsigned short* Kb  = (unsigned short*)(ws + 40 * MB);
        unsigned short* Vb  = (unsigned short*)(ws + 48 * MB);

        wtrans_kernel<<<dim3(16, 16, 4), 256, 0, stream>>>(W_q, W_k, W_v, W_o, Wt4);
        hconv_kernel<<<dim3(2048, 3), 256, 0, stream>>>(H_q, H_k, H_v, Hbf);
        gemm_glds_kernel<<<768, 256, 0, stream>>>(
            Hbf, Wt4, b_q, b_k, b_v, scale, 1.0f, Qb);
        colsum_kernel<<<1024, 256, 0, stream>>>(Qb, Kb, Vb, Vt);
        attn_kernel<<<512, 512, 0, stream>>>(Qb, Kb, Vt, Ctx);
        gemm_o64_kernel<<<512, 256, 0, stream>>>(
            Ctx, Wt4 + (size_t)3 * 1024 * 1024, b_o, (float*)d_out);
    } else {
        unsigned short* Qb  = (unsigned short*)(ws + 0 * MB);
        unsigned short* Kb  = (unsigned short*)(ws + 8 * MB);
        unsigned short* Vt  = (unsigned short*)(ws + 16 * MB);
        unsigned short* Vb  = (unsigned short*)(ws + 24 * MB);
        unsigned short* Ctx = (unsigned short*)(ws + 24 * MB);
        unsigned short* Wt4 = (unsigned short*)(ws + 32 * MB);

        wtrans_kernel<<<dim3(16, 16, 4), 256, 0, stream>>>(W_q, W_k, W_v, W_o, Wt4);
        gemm_bt_kernel<false, true><<<dim3(8, 32), 256, 0, stream>>>(H_q, Wt4, b_q, scale, Qb);
        gemm_bt_kernel<false, true><<<dim3(8, 32), 256, 0, stream>>>(H_k, Wt4 + (size_t)1024 * 1024, b_k, scale, Kb);
        gemm_bt_kernel<false, true><<<dim3(8, 32), 256, 0, stream>>>(H_v, Wt4 + (size_t)2 * 1024 * 1024, b_v, 1.0f, Vb);
        colsum_kernel<<<1024, 256, 0, stream>>>(Qb, Kb, Vb, Vt);
        attn_kernel<<<512, 512, 0, stream>>>(Qb, Kb, Vt, Ctx);
        gemm_bt_kernel<true, false><<<dim3(8, 32), 256, 0, stream>>>(Ctx, Wt4 + (size_t)3 * 1024 * 1024, b_o, 1.0f, d_out);
    }
}

// Round 15
// 139.541 us; speedup vs baseline: 1.2151x; 1.0189x over previous
//
#include <hip/hip_runtime.h>

#define L 2048
#define HSZ 1024
#define HDIM 64
// 32 head-panels total (N=2 batches x 16 heads), each a contiguous [2048][64]

typedef float f32x4 __attribute__((ext_vector_type(4)));
typedef short short8v __attribute__((ext_vector_type(8)));

static __device__ __forceinline__ unsigned short f2bf(float f) {
    unsigned int u = __builtin_bit_cast(unsigned int, f);
    u += 0x7FFFu + ((u >> 16) & 1u);   // RNE
    return (unsigned short)(u >> 16);
}
static __device__ __forceinline__ float bf2f(unsigned short u) {
    return __builtin_bit_cast(float, (unsigned int)u << 16);
}
static __device__ __forceinline__ unsigned int cvt_pk_bf16(float lo, float hi) {
    unsigned int r;
    asm("v_cvt_pk_bf16_f32 %0, %1, %2" : "=v"(r) : "v"(lo), "v"(hi));
    return r;
}
static __device__ __forceinline__ void gload_lds16(const void* g, void* l) {
    __builtin_amdgcn_global_load_lds(
        (const __attribute__((address_space(1))) unsigned int*)g,
        (__attribute__((address_space(3))) unsigned int*)l, 16, 0, 0);
}

// ---------------------------------------------------------------------------
// PREP (merged): blocks [0,6144) convert H_q/H_k/H_v fp32 -> bf16 Hbf;
// blocks [6144,7168) transpose+convert weights Wt4[z][n][k] = bf16(W_z[k][n]).
// Branch is blockIdx-uniform, so the divergent __syncthreads is legal.
// ---------------------------------------------------------------------------
__global__ __launch_bounds__(256) void prep_kernel(
    const float* __restrict__ H0, const float* __restrict__ H1,
    const float* __restrict__ H2, unsigned short* __restrict__ Hbf,
    const float* __restrict__ W0, const float* __restrict__ W1,
    const float* __restrict__ W2, const float* __restrict__ W3,
    unsigned short* __restrict__ Wt4)
{
    int b = blockIdx.x;
    int t = threadIdx.x;
    if (b < 6144) {
        int z = b >> 11;                 // 0..2
        int xb = b & 2047;
        const float* S = (z == 0) ? H0 : (z == 1) ? H1 : H2;
        size_t base = ((size_t)xb * 256 + t) * 8;
        unsigned short* D = Hbf + (size_t)z * (4096 * 1024) + base;
        float4 a = *(const float4*)(S + base);
        float4 bb = *(const float4*)(S + base + 4);
        unsigned short o[8] = {f2bf(a.x), f2bf(a.y), f2bf(a.z), f2bf(a.w),
                               f2bf(bb.x), f2bf(bb.y), f2bf(bb.z), f2bf(bb.w)};
        *(uint4*)D = *(const uint4*)o;
    } else {
        int q = b - 6144;                // 0..1023
        int z = q >> 8;
        int rem = q & 255;
        int k0 = (rem >> 4) * 64, n0 = (rem & 15) * 64;
        const float* W = (z == 0) ? W0 : (z == 1) ? W1 : (z == 2) ? W2 : W3;
        unsigned short* T = Wt4 + (size_t)z * HSZ * HSZ;

        __shared__ __align__(16) unsigned short tl[64][72];
        int kl = t >> 2, nc = (t & 3) * 16;
        const float* src = W + (size_t)(k0 + kl) * HSZ + n0 + nc;
#pragma unroll
        for (int qq = 0; qq < 4; qq++) {
            float4 v = ((const float4*)src)[qq];
            tl[kl][nc + qq * 4 + 0] = f2bf(v.x);
            tl[kl][nc + qq * 4 + 1] = f2bf(v.y);
            tl[kl][nc + qq * 4 + 2] = f2bf(v.z);
            tl[kl][nc + qq * 4 + 3] = f2bf(v.w);
        }
        __syncthreads();
        int nl = t >> 2, kc = (t & 3) * 16;
        unsigned short tmp[16];
#pragma unroll
        for (int e = 0; e < 16; e++) tmp[e] = tl[kc + e][nl];
        unsigned short* dst = T + (size_t)(n0 + nl) * HSZ + k0 + kc;
        ((uint4*)dst)[0] = *(uint4*)&tmp[0];
        ((uint4*)dst)[1] = *(uint4*)&tmp[8];
    }
}

// ---------------------------------------------------------------------------
// Weights-only transpose (fallback path).
// ---------------------------------------------------------------------------
__global__ __launch_bounds__(256) void wtrans_kernel(
    const float* __restrict__ W0, const float* __restrict__ W1,
    const float* __restrict__ W2, const float* __restrict__ W3,
    unsigned short* __restrict__ Wt4)
{
    const float* W;
    int z = blockIdx.z;
    if (z == 0) W = W0; else if (z == 1) W = W1; else if (z == 2) W = W2; else W = W3;
    unsigned short* T = Wt4 + (size_t)z * HSZ * HSZ;

    __shared__ __align__(16) unsigned short tl[64][72];
    int t = threadIdx.x;
    int k0 = blockIdx.y * 64, n0 = blockIdx.x * 64;

    int kl = t >> 2, nc = (t & 3) * 16;
    const float* src = W + (size_t)(k0 + kl) * HSZ + n0 + nc;
#pragma unroll
    for (int q = 0; q < 4; q++) {
        float4 v = ((const float4*)src)[q];
        tl[kl][nc + q * 4 + 0] = f2bf(v.x);
        tl[kl][nc + q * 4 + 1] = f2bf(v.y);
        tl[kl][nc + q * 4 + 2] = f2bf(v.z);
        tl[kl][nc + q * 4 + 3] = f2bf(v.w);
    }
    __syncthreads();
    int nl = t >> 2, kc = (t & 3) * 16;
    unsigned short tmp[16];
#pragma unroll
    for (int e = 0; e < 16; e++) tmp[e] = tl[kc + e][nl];
    unsigned short* dst = T + (size_t)(n0 + nl) * HSZ + k0 + kc;
    ((uint4*)dst)[0] = *(uint4*)&tmp[0];
    ((uint4*)dst)[1] = *(uint4*)&tmp[8];
}

// ---------------------------------------------------------------------------
// QKV GEMM (bf16 out), single-barrier dbuf pipeline, XCD-slab swizzle.
// ---------------------------------------------------------------------------
__global__ __launch_bounds__(256) void gemm_glds_kernel(
    const unsigned short* __restrict__ A, const unsigned short* __restrict__ B,
    const float* __restrict__ bias0, const float* __restrict__ bias1,
    const float* __restrict__ bias2, float scale01, float scale2,
    unsigned short* __restrict__ outbase)
{
    __shared__ __align__(16) unsigned short As[2][4096];
    __shared__ __align__(16) unsigned short Bs[2][4096];

    int raw = blockIdx.x;
    int xcd = raw & 7, idx = raw >> 3;       // idx in [0,96)
    int mb = (xcd * 4 + (idx & 3)) * 128;    // 4 mb-slabs per XCD
    int col = idx >> 2;                      // 0..23
    int proj = col >> 3;
    int nb = (col & 7) * 128;

    int t = threadIdx.x;
    int lane = t & 63, w = t >> 6;
    int lr = lane & 15, lg = lane >> 4;
    int wm = (w >> 1) * 64, wn = (w & 1) * 64;

    const unsigned short* Ap = A + (size_t)proj * (4096 * 1024);
    const unsigned short* Bp = B + (size_t)proj * (1024 * 1024);
    const float* bias = (proj == 0) ? bias0 : (proj == 1) ? bias1 : bias2;
    float scale = (proj < 2) ? scale01 : scale2;

    int c0 = w * 64 + lane;
    int r0 = c0 >> 2, e0 = (c0 & 3) * 8;
    int r1 = r0 + 64;
    const unsigned short* gA0 = Ap + (size_t)(mb + r0) * HSZ + e0;
    const unsigned short* gA1 = Ap + (size_t)(mb + r1) * HSZ + e0;
    const unsigned short* gB0 = Bp + (size_t)(nb + r0) * HSZ + e0;
    const unsigned short* gB1 = Bp + (size_t)(nb + r1) * HSZ + e0;

    f32x4 acc[4][4] = {};

    auto stage = [&](int buf, int kt) {
        gload_lds16(gA0 + kt, &As[buf][w * 512]);
        gload_lds16(gA1 + kt, &As[buf][2048 + w * 512]);
        gload_lds16(gB0 + kt, &Bs[buf][w * 512]);
        gload_lds16(gB1 + kt, &Bs[buf][2048 + w * 512]);
    };

    stage(0, 0);
    __syncthreads();

    int buf = 0;
    for (int kt = 0; kt < HSZ; kt += 32) {
        if (kt + 32 < HSZ) stage(buf ^ 1, kt + 32);

        short8v af[4], bfv[4];
#pragma unroll
        for (int s = 0; s < 4; s++) {
            af[s]  = *(const short8v*)&As[buf][(wm + s * 16 + lr) * 32 + lg * 8];
            bfv[s] = *(const short8v*)&Bs[buf][(wn + s * 16 + lr) * 32 + lg * 8];
        }
#pragma unroll
        for (int i = 0; i < 4; i++)
#pragma unroll
            for (int j = 0; j < 4; j++)
                acc[i][j] = __builtin_amdgcn_mfma_f32_16x16x32_bf16(af[i], bfv[j], acc[i][j], 0, 0, 0);
        __syncthreads();   // drains stage vmcnt + all reads of buf
        buf ^= 1;
    }

#pragma unroll
    for (int j = 0; j < 4; j++) {
        int colo = nb + wn + j * 16 + lr;
        float bv = bias[colo];
#pragma unroll
        for (int i = 0; i < 4; i++) {
            int row0 = mb + wm + i * 16 + lg * 4;
#pragma unroll
            for (int rg = 0; rg < 4; rg++) {
                float v = (acc[i][j][rg] + bv) * scale;
                outbase[(size_t)proj * (4096 * 1024) + (size_t)(row0 + rg) * HSZ + colo] = f2bf(v);
            }
        }
    }
}

// ---------------------------------------------------------------------------
// Output GEMM: fp32 out, BM=64 x BN=64 tiles -> 1024 blocks (4/CU) for
// latency overlap. Per-XCD working set: A 1 MB + B 2 MB < 4 MB L2.
// ---------------------------------------------------------------------------
__global__ __launch_bounds__(256) void gemm_o64_kernel(
    const unsigned short* __restrict__ A, const unsigned short* __restrict__ B,
    const float* __restrict__ bias, float* __restrict__ out)
{
    __shared__ __align__(16) unsigned short As[2][2048];
    __shared__ __align__(16) unsigned short Bs[2][2048];

    int raw = blockIdx.x;
    int xcd = raw & 7, idx = raw >> 3;       // idx in [0,128)
    int mb = (xcd * 8 + (idx & 7)) * 64;     // 8 mb-slabs per XCD (512 rows)
    int nb = (idx >> 3) * 64;                // 16 n-columns

    int t = threadIdx.x;
    int lane = t & 63, w = t >> 6;
    int lr = lane & 15, lg = lane >> 4;
    int wm = (w >> 1) * 32, wn = (w & 1) * 32;

    int c0 = w * 64 + lane;                  // 0..255
    int r0 = c0 >> 2, e0 = (c0 & 3) * 8;     // 64 rows x 4 chunks
    const unsigned short* gA0 = A + (size_t)(mb + r0) * HSZ + e0;
    const unsigned short* gB0 = B + (size_t)(nb + r0) * HSZ + e0;

    f32x4 acc[2][2] = {};

    auto stage = [&](int buf, int kt) {
        gload_lds16(gA0 + kt, &As[buf][w * 512]);
        gload_lds16(gB0 + kt, &Bs[buf][w * 512]);
    };

    stage(0, 0);
    __syncthreads();

    int buf = 0;
    for (int kt = 0; kt < HSZ; kt += 32) {
        if (kt + 32 < HSZ) stage(buf ^ 1, kt + 32);

        short8v af[2], bfv[2];
#pragma unroll
        for (int s = 0; s < 2; s++) {
            af[s]  = *(const short8v*)&As[buf][(wm + s * 16 + lr) * 32 + lg * 8];
            bfv[s] = *(const short8v*)&Bs[buf][(wn + s * 16 + lr) * 32 + lg * 8];
        }
#pragma unroll
        for (int i = 0; i < 2; i++)
#pragma unroll
            for (int j = 0; j < 2; j++)
                acc[i][j] = __builtin_amdgcn_mfma_f32_16x16x32_bf16(af[i], bfv[j], acc[i][j], 0, 0, 0);
        __syncthreads();
        buf ^= 1;
    }

#pragma unroll
    for (int j = 0; j < 2; j++) {
        int colo = nb + wn + j * 16 + lr;
        float bv = bias[colo];
#pragma unroll
        for (int i = 0; i < 2; i++) {
            int row0 = mb + wm + i * 16 + lg * 4;
#pragma unroll
            for (int rg = 0; rg < 4; rg++)
                out[(size_t)(row0 + rg) * HSZ + colo] = acc[i][j][rg] + bv;
        }
    }
}

// ---------------------------------------------------------------------------
// Legacy fp32-A GEMM (fallback path if ws is small).
// ---------------------------------------------------------------------------
template<bool ABF16, bool OUTBF16>
__global__ __launch_bounds__(256) void gemm_bt_kernel(
    const void* __restrict__ Aptr, const unsigned short* __restrict__ Bt,
    const float* __restrict__ bias, float scale, void* __restrict__ outp)
{
    __shared__ __align__(16) unsigned short As[128][40];
    __shared__ __align__(16) unsigned short Bs[128][40];

    int t = threadIdx.x;
    int lane = t & 63, w = t >> 6;
    int lr = lane & 15, lg = lane >> 4;
    int mb = blockIdx.y * 128, nb = blockIdx.x * 128;
    int wm = (w >> 1) * 64, wn = (w & 1) * 64;
    int r = t >> 1, cc = (t & 1) * 16;

    f32x4 acc[4][4] = {};

    for (int kt = 0; kt < HSZ; kt += 32) {
        if (ABF16) {
            const unsigned short* A = (const unsigned short*)Aptr + (size_t)(mb + r) * HSZ + kt + cc;
            *(uint4*)&As[r][cc]     = ((const uint4*)A)[0];
            *(uint4*)&As[r][cc + 8] = ((const uint4*)A)[1];
        } else {
            const float* A = (const float*)Aptr + (size_t)(mb + r) * HSZ + kt + cc;
            unsigned short tmp[16];
#pragma unroll
            for (int q = 0; q < 4; q++) {
                float4 v = ((const float4*)A)[q];
                tmp[q * 4 + 0] = f2bf(v.x); tmp[q * 4 + 1] = f2bf(v.y);
                tmp[q * 4 + 2] = f2bf(v.z); tmp[q * 4 + 3] = f2bf(v.w);
            }
            *(uint4*)&As[r][cc]     = *(uint4*)&tmp[0];
            *(uint4*)&As[r][cc + 8] = *(uint4*)&tmp[8];
        }
        {
            const unsigned short* B = Bt + (size_t)(nb + r) * HSZ + kt + cc;
            *(uint4*)&Bs[r][cc]     = ((const uint4*)B)[0];
            *(uint4*)&Bs[r][cc + 8] = ((const uint4*)B)[1];
        }
        __syncthreads();

        short8v af[4], bf[4];
#pragma unroll
        for (int s = 0; s < 4; s++) af[s] = *(const short8v*)&As[wm + s * 16 + lr][8 * lg];
#pragma unroll
        for (int s = 0; s < 4; s++) bf[s] = *(const short8v*)&Bs[wn + s * 16 + lr][8 * lg];
#pragma unroll
        for (int i = 0; i < 4; i++)
#pragma unroll
            for (int j = 0; j < 4; j++)
                acc[i][j] = __builtin_amdgcn_mfma_f32_16x16x32_bf16(af[i], bf[j], acc[i][j], 0, 0, 0);
        __syncthreads();
    }

#pragma unroll
    for (int j = 0; j < 4; j++) {
        int col = nb + wn + j * 16 + lr;
        float bv = bias[col];
#pragma unroll
        for (int i = 0; i < 4; i++) {
            int row0 = mb + wm + i * 16 + lg * 4;
#pragma unroll
            for (int rg = 0; rg < 4; rg++) {
                float v = (acc[i][j][rg] + bv) * scale;
                if (OUTBF16)
                    ((unsigned short*)outp)[(size_t)(row0 + rg) * HSZ + col] = f2bf(v);
                else
                    ((float*)outp)[(size_t)(row0 + rg) * HSZ + col] = v;
            }
        }
    }
}

// ---------------------------------------------------------------------------
// Phase 1 FUSED (colsum + vtrans), R14-proven: 2-deep Q prefetch,
// complementary jb pairing, LDS rcpC broadcast, folded V transpose.
// ---------------------------------------------------------------------------
__global__ __launch_bounds__(256) void colsum_kernel(
    const unsigned short* __restrict__ Qb, const unsigned short* __restrict__ Kb,
    const unsigned short* __restrict__ Vb, unsigned short* __restrict__ Vt)
{
    int raw = blockIdx.x;
    int xcd = raw & 7, idx = raw >> 3;        // idx in [0,128)
    int head = xcd * 4 + (idx >> 5);          // 4 heads per XCD
    int jbi = idx & 31;
    if ((idx >> 5) & 1) jbi = 31 - jbi;       // complementary per co-resident set
    int jb = jbi * 64;
    const unsigned short* Qh = Qb + (size_t)head * L * HDIM;
    const unsigned short* Kh = Kb + (size_t)head * L * HDIM;
    int t = threadIdx.x, lane = t & 63, w = t >> 6;
    int lr = lane & 15, lg = lane >> 4;

    short8v af[4][2];
#pragma unroll
    for (int sj = 0; sj < 4; sj++)
#pragma unroll
        for (int kk = 0; kk < 2; kk++)
            af[sj][kk] = *(const short8v*)&Kh[(size_t)(jb + sj * 16 + lr) * HDIM + kk * 32 + 8 * lg];

    float accs[4][4] = {};

    int it0 = jb + w * 16;
    short8v a0 = *(const short8v*)&Qh[(size_t)(it0 + lr) * HDIM + 8 * lg];
    short8v a1 = *(const short8v*)&Qh[(size_t)(it0 + lr) * HDIM + 32 + 8 * lg];
    int itB = (it0 + 64 < L) ? it0 + 64 : it0;
    short8v b0 = *(const short8v*)&Qh[(size_t)(itB + lr) * HDIM + 8 * lg];
    short8v b1 = *(const short8v*)&Qh[(size_t)(itB + lr) * HDIM + 32 + 8 * lg];

    for (int it = it0; it < L; it += 64) {
        int itC = (it + 128 < L) ? it + 128 : it;
        short8v cv0 = *(const short8v*)&Qh[(size_t)(itC + lr) * HDIM + 8 * lg];
        short8v cv1 = *(const short8v*)&Qh[(size_t)(itC + lr) * HDIM + 32 + 8 * lg];
        if (it == it0) {   // diagonal-overlap iteration: masked
            int i = it + lr;
#pragma unroll
            for (int sj = 0; sj < 4; sj++) {
                f32x4 d = {0.0f, 0.0f, 0.0f, 0.0f};
                d = __builtin_amdgcn_mfma_f32_16x16x32_bf16(af[sj][0], a0, d, 0, 0, 0);
                d = __builtin_amdgcn_mfma_f32_16x16x32_bf16(af[sj][1], a1, d, 0, 0, 0);
#pragma unroll
                for (int rg = 0; rg < 4; rg++) {
                    int j = jb + sj * 16 + lg * 4 + rg;
                    if (i >= j) accs[sj][rg] += __expf(d[rg]);
                }
            }
        } else {           // interior: i >= jb+64 > jmax, no mask
#pragma unroll
            for (int sj = 0; sj < 4; sj++) {
                f32x4 d = {0.0f, 0.0f, 0.0f, 0.0f};
                d = __builtin_amdgcn_mfma_f32_16x16x32_bf16(af[sj][0], a0, d, 0, 0, 0);
                d = __builtin_amdgcn_mfma_f32_16x16x32_bf16(af[sj][1], a1, d, 0, 0, 0);
#pragma unroll
                for (int rg = 0; rg < 4; rg++)
                    accs[sj][rg] += __expf(d[rg]);
            }
        }
        a0 = b0; a1 = b1; b0 = cv0; b1 = cv1;
    }

    __shared__ float part[4][64];
    __shared__ float rc64[64];
#pragma unroll
    for (int sj = 0; sj < 4; sj++)
#pragma unroll
        for (int rg = 0; rg < 4; rg++) {
            float v = accs[sj][rg];
            v += __shfl_xor(v, 1); v += __shfl_xor(v, 2);
            v += __shfl_xor(v, 4); v += __shfl_xor(v, 8);
            if (lr == 0) part[w][sj * 16 + lg * 4 + rg] = v;
        }
    __syncthreads();
    if (t < 64) {
        float s = part[0][t] + part[1][t] + part[2][t] + part[3][t];
        rc64[t] = 1.0f / s;
    }
    __syncthreads();

    // ---- fused vtrans for this (head, jb): Vt[c][jb+j] = V[jb+j][c]*rc ----
    __shared__ __align__(16) unsigned short tl[64][72];
    const unsigned short* Vp = Vb + (size_t)head * L * HDIM;
    unsigned short* Tp = Vt + (size_t)head * HDIM * L;
    int jl = t >> 2, c0 = (t & 3) * 16;
    float rcv = rc64[jl];
    const unsigned short* src = Vp + (size_t)(jb + jl) * HDIM + c0;
    unsigned short rawv[16];
    *(uint4*)&rawv[0] = ((const uint4*)src)[0];
    *(uint4*)&rawv[8] = ((const uint4*)src)[1];
#pragma unroll
    for (int e = 0; e < 16; e++) tl[jl][c0 + e] = f2bf(bf2f(rawv[e]) * rcv);
    __syncthreads();
    int cl = t >> 2, jc = (t & 3) * 16;
    unsigned short tmp[16];
#pragma unroll
    for (int e = 0; e < 16; e++) tmp[e] = tl[jc + e][cl];
    unsigned short* dst = Tp + (size_t)cl * L + jb + jc;
    ((uint4*)dst)[0] = *(uint4*)&tmp[0];
    ((uint4*)dst)[1] = *(uint4*)&tmp[8];
}

// ---------------------------------------------------------------------------
// Phase 2 (LDS-staged flash loop, 8 waves): block covers 128 q-rows.
// EXACT R9 version (proven): complementary pairing via idx bit5 XOR into
// snake parity; diagonal-only masking; XOR-swizzled dbuf LDS staging.
// ---------------------------------------------------------------------------
__global__ __launch_bounds__(512) void attn_kernel(
    const unsigned short* __restrict__ Qb, const unsigned short* __restrict__ Kb,
    const unsigned short* __restrict__ Vtg, unsigned short* __restrict__ Ctx)
{
    int raw = blockIdx.x;
    int xcd = raw & 7, idx = raw >> 3;            // idx in [0,64)
    int head = xcd * 4 + (idx >> 4);              // 4 heads per XCD
    int jpos = (idx & 15) ^ ((idx >> 5) & 1);     // complementary per co-resident pair
    int qtile = (jpos & 1) ? (jpos >> 1) : (15 - (jpos >> 1));   // snake
    int qb = qtile * 128;
    int nt = qb / 64 + 2;                          // KV tiles this block touches

    const unsigned short* Qh = Qb + (size_t)head * L * HDIM;
    const unsigned short* Kh = Kb + (size_t)head * L * HDIM;
    const unsigned short* Vh = Vtg + (size_t)head * HDIM * L;   // [64][2048]
    unsigned short* Ch = Ctx + (size_t)head * L * HDIM;

    int t = threadIdx.x;
    int lane = t & 63, w = t >> 6;
    int ws = w & 3;                                // strip
    int w2 = w >> 2;                               // which 32-j window
    int lr = lane & 15, lg = lane >> 4;
    int iw = qb + ws * 32;
    int src0 = ((lane & 16) << 1) + lr;
    int src1 = src0 + 16;
    bool jlow = (lg < 2);

    // SMEM[0..1] = Kt dbuf, SMEM[2..3] = Vl dbuf; reused as f32x4 dump at end
    __shared__ __align__(16) unsigned short SMEM[4][4096];

    int srow = ws * 8 + (lane >> 3);
    int soff = ((lane & 7) ^ (lane >> 3)) * 8;     // pre-XORed source offset

    auto stageT = [&](int buf, int jt) {
        if (w < 4) {
            gload_lds16(Kh + (size_t)(jt + srow) * HDIM + soff,      &SMEM[buf][ws * 512]);
            gload_lds16(Kh + (size_t)(jt + srow + 32) * HDIM + soff, &SMEM[buf][ws * 512 + 2048]);
        } else {
            gload_lds16(Vh + (size_t)srow * L + jt + soff,           &SMEM[2 + buf][ws * 512]);
            gload_lds16(Vh + (size_t)(srow + 32) * L + jt + soff,    &SMEM[2 + buf][ws * 512 + 2048]);
        }
    };

    short8v bq[2][2];
#pragma unroll
    for (int isub = 0; isub < 2; isub++)
#pragma unroll
        for (int kd = 0; kd < 2; kd++)
            bq[isub][kd] = *(const short8v*)&Qh[(size_t)(iw + isub * 16 + lr) * HDIM + kd * 32 + 8 * lg];

    f32x4 acc[4][2] = {};   // ctx^T [csub][isub]: D(c=lg*4+rg, i=lr)

    stageT(0, 0);
    __syncthreads();

    for (int tt = 0; tt < nt; ++tt) {
        int buf = tt & 1;
        if (tt + 1 < nt) stageT(buf ^ 1, (tt + 1) * 64);

        int jt32 = tt * 64 + w2 * 32;
        if (jt32 <= iw + 31) {
            short8v ak[2][2];
#pragma unroll
            for (int jsub = 0; jsub < 2; jsub++)
#pragma unroll
                for (int kd = 0; kd < 2; kd++) {
                    int lrow = w2 * 32 + jsub * 16 + lr;
                    int off = lrow * 64 + ((((kd << 2) | lg) ^ (lr & 7)) << 3);
                    ak[jsub][kd] = *(const short8v*)&SMEM[buf][off];
                }
            short8v av[4];
#pragma unroll
            for (int csub = 0; csub < 4; csub++) {
                int vrow = csub * 16 + lr;
                int off = vrow * 64 + ((((w2 << 2) | lg) ^ (lr & 7)) << 3);
                av[csub] = *(const short8v*)&SMEM[2 + buf][off];
            }

            unsigned int pk[2][2][2];   // [jsub][isub][word]
            if (jt32 == iw) {           // the single diagonal window: masked
#pragma unroll
                for (int jsub = 0; jsub < 2; jsub++)
#pragma unroll
                    for (int isub = 0; isub < 2; isub++) {
                        f32x4 s = {0.0f, 0.0f, 0.0f, 0.0f};
                        s = __builtin_amdgcn_mfma_f32_16x16x32_bf16(ak[jsub][0], bq[isub][0], s, 0, 0, 0);
                        s = __builtin_amdgcn_mfma_f32_16x16x32_bf16(ak[jsub][1], bq[isub][1], s, 0, 0, 0);
                        int i = iw + isub * 16 + lr;
                        int jb0 = jt32 + jsub * 16 + lg * 4;
                        float p[4];
#pragma unroll
                        for (int rg = 0; rg < 4; rg++)
                            p[rg] = (jb0 + rg <= i) ? __expf(s[rg]) : 0.0f;
                        pk[jsub][isub][0] = cvt_pk_bf16(p[0], p[1]);
                        pk[jsub][isub][1] = cvt_pk_bf16(p[2], p[3]);
                    }
            } else {                    // interior: j < iw <= i, no mask
#pragma unroll
                for (int jsub = 0; jsub < 2; jsub++)
#pragma unroll
                    for (int isub = 0; isub < 2; isub++) {
                        f32x4 s = {0.0f, 0.0f, 0.0f, 0.0f};
                        s = __builtin_amdgcn_mfma_f32_16x16x32_bf16(ak[jsub][0], bq[isub][0], s, 0, 0, 0);
                        s = __builtin_amdgcn_mfma_f32_16x16x32_bf16(ak[jsub][1], bq[isub][1], s, 0, 0, 0);
                        pk[jsub][isub][0] = cvt_pk_bf16(__expf(s[0]), __expf(s[1]));
                        pk[jsub][isub][1] = cvt_pk_bf16(__expf(s[2]), __expf(s[3]));
                    }
            }
            __builtin_amdgcn_s_setprio(1);
#pragma unroll
            for (int isub = 0; isub < 2; isub++) {
                int a0 = __shfl((int)pk[0][isub][0], src0);
                int a1 = __shfl((int)pk[0][isub][1], src0);
                int a2 = __shfl((int)pk[0][isub][0], src1);
                int a3 = __shfl((int)pk[0][isub][1], src1);
                int b0 = __shfl((int)pk[1][isub][0], src0);
                int b1 = __shfl((int)pk[1][isub][1], src0);
                int b2 = __shfl((int)pk[1][isub][0], src1);
                int b3 = __shfl((int)pk[1][isub][1], src1);
                int4 wvv;
                wvv.x = jlow ? a0 : b0;
                wvv.y = jlow ? a1 : b1;
                wvv.z = jlow ? a2 : b2;
                wvv.w = jlow ? a3 : b3;
                short8v bp = __builtin_bit_cast(short8v, wvv);
#pragma unroll
                for (int csub = 0; csub < 4; csub++)
                    acc[csub][isub] = __builtin_amdgcn_mfma_f32_16x16x32_bf16(av[csub], bp, acc[csub][isub], 0, 0, 0);
            }
            __builtin_amdgcn_s_setprio(0);
        }
        __syncthreads();   // stage(t+1) drained + all reads of buf done
    }

    // cross-wave pair reduction: waves 4-7 dump acc to LDS, waves 0-3 add+store
    uint4* red = (uint4*)SMEM;   // 2048 uint4 = 32 KB
    if (w >= 4) {
#pragma unroll
        for (int csub = 0; csub < 4; csub++)
#pragma unroll
            for (int isub = 0; isub < 2; isub++)
                red[((ws * 8) + csub * 2 + isub) * 64 + lane] =
                    __builtin_bit_cast(uint4, acc[csub][isub]);
    }
    __syncthreads();
    if (w < 4) {
#pragma unroll
        for (int csub = 0; csub < 4; csub++)
#pragma unroll
            for (int isub = 0; isub < 2; isub++)
                acc[csub][isub] += __builtin_bit_cast(f32x4,
                    red[((ws * 8) + csub * 2 + isub) * 64 + lane]);

#pragma unroll
        for (int csub = 0; csub < 4; csub++)
#pragma unroll
            for (int isub = 0; isub < 2; isub++) {
                int i = iw + isub * 16 + lr;
                int c0 = csub * 16 + lg * 4;
                unsigned short t4[4];
#pragma unroll
                for (int rg = 0; rg < 4; rg++) t4[rg] = f2bf(acc[csub][isub][rg]);
                *(uint2*)&Ch[(size_t)i * HDIM + c0] = *(uint2*)t4;
            }
    }
}

// ---------------------------------------------------------------------------
extern "C" void kernel_launch(void* const* d_in, const int* in_sizes, int n_in,
                              void* d_out, int out_size, void* d_ws, size_t ws_size,
                              hipStream_t stream)
{
    const float* H_q = (const float*)d_in[0];
    const float* H_k = (const float*)d_in[1];
    const float* H_v = (const float*)d_in[2];
    const float* W_q = (const float*)d_in[3];
    const float* b_q = (const float*)d_in[4];
    const float* W_k = (const float*)d_in[5];
    const float* b_k = (const float*)d_in[6];
    const float* W_v = (const float*)d_in[7];
    const float* b_v = (const float*)d_in[8];
    const float* W_o = (const float*)d_in[9];
    const float* b_o = (const float*)d_in[10];

    char* ws = (char*)d_ws;
    const size_t MB = (size_t)1 << 20;
    const float scale = 0.03125f;  // 1/sqrt(1024)

    if (ws_size >= 60 * MB) {
        unsigned short* Hbf = (unsigned short*)(ws);
        unsigned short* Vt  = (unsigned short*)(ws);
        unsigned short* Ctx = (unsigned short*)(ws + 8 * MB);
        unsigned short* Wt4 = (unsigned short*)(ws + 24 * MB);
        unsigned short* Qb  = (unsigned short*)(ws + 32 * MB);
        unsigned short* Kb  = (unsigned short*)(ws + 40 * MB);
        unsigned short* Vb  = (unsigned short*)(ws + 48 * MB);

        prep_kernel<<<7168, 256, 0, stream>>>(H_q, H_k, H_v, Hbf,
                                              W_q, W_k, W_v, W_o, Wt4);
        gemm_glds_kernel<<<768, 256, 0, stream>>>(
            Hbf, Wt4, b_q, b_k, b_v, scale, 1.0f, Qb);
        colsum_kernel<<<1024, 256, 0, stream>>>(Qb, Kb, Vb, Vt);
        attn_kernel<<<512, 512, 0, stream>>>(Qb, Kb, Vt, Ctx);
        gemm_o64_kernel<<<1024, 256, 0, stream>>>(
            Ctx, Wt4 + (size_t)3 * 1024 * 1024, b_o, (float*)d_out);
    } else {
        unsigned short* Qb  = (unsigned short*)(ws + 0 * MB);
        unsigned short* Kb  = (unsigned short*)(ws + 8 * MB);
        unsigned short* Vt  = (unsigned short*)(ws + 16 * MB);
        unsigned short* Vb  = (unsigned short*)(ws + 24 * MB);
        unsigned short* Ctx = (unsigned short*)(ws + 24 * MB);
        unsigned short* Wt4 = (unsigned short*)(ws + 32 * MB);

        wtrans_kernel<<<dim3(16, 16, 4), 256, 0, stream>>>(W_q, W_k, W_v, W_o, Wt4);
        gemm_bt_kernel<false, true><<<dim3(8, 32), 256, 0, stream>>>(H_q, Wt4, b_q, scale, Qb);
        gemm_bt_kernel<false, true><<<dim3(8, 32), 256, 0, stream>>>(H_k, Wt4 + (size_t)1024 * 1024, b_k, scale, Kb);
        gemm_bt_kernel<false, true><<<dim3(8, 32), 256, 0, stream>>>(H_v, Wt4 + (size_t)2 * 1024 * 1024, b_v, 1.0f, Vb);
        colsum_kernel<<<1024, 256, 0, stream>>>(Qb, Kb, Vb, Vt);
        attn_kernel<<<512, 512, 0, stream>>>(Qb, Kb, Vt, Ctx);
        gemm_bt_kernel<true, false><<<dim3(8, 32), 256, 0, stream>>>(Ctx, Wt4 + (size_t)3 * 1024 * 1024, b_o, 1.0f, d_out);
    }
}